// Round 1
// baseline (667.281 us; speedup 1.0000x reference)
//
#include <hip/hip_runtime.h>
#include <cstdint>

typedef __attribute__((ext_vector_type(8))) __bf16 bf16x8;
typedef __attribute__((ext_vector_type(4))) float f32x4;

__device__ __forceinline__ unsigned short f2bf(float f) {
  unsigned u = __float_as_uint(f);
  unsigned r = (u + 0x7FFFu + ((u >> 16) & 1u)) >> 16;  // RNE
  return (unsigned short)r;
}
__device__ __forceinline__ float bf2f(unsigned short u) {
  return __uint_as_float(((unsigned)u) << 16);
}

__device__ __forceinline__ __attribute__((address_space(3))) void* to_lds(void* p) {
  return (__attribute__((address_space(3))) void*)p;
}
__device__ __forceinline__ const __attribute__((address_space(1))) void* to_glb(const void* p) {
  return (const __attribute__((address_space(1))) void*)p;
}

// ---------------- transpose: fp32 in[R,C] -> bf16 out[C,R] ----------------
__global__ void k_transpose_bf16(const float* __restrict__ in, unsigned short* __restrict__ out,
                                 int R, int C) {
  __shared__ float tile[32][33];
  int c0 = blockIdx.x * 32, r0 = blockIdx.y * 32;
  int tx = threadIdx.x, ty = threadIdx.y;  // block (32,8)
  #pragma unroll
  for (int i = 0; i < 32; i += 8)
    tile[ty + i][tx] = in[(size_t)(r0 + ty + i) * C + c0 + tx];
  __syncthreads();
  #pragma unroll
  for (int i = 0; i < 32; i += 8)
    out[(size_t)(c0 + ty + i) * R + r0 + tx] = f2bf(tile[tx][ty + i]);
}

// ---------------- fp32 -> bf16 contiguous ----------------
__global__ void k_convert_bf16(const float4* __restrict__ in, ushort4* __restrict__ out, int n4) {
  int i = blockIdx.x * blockDim.x + threadIdx.x;
  if (i < n4) {
    float4 v = in[i];
    ushort4 o; o.x = f2bf(v.x); o.y = f2bf(v.y); o.z = f2bf(v.z); o.w = f2bf(v.w);
    out[i] = o;
  }
}

// ---------------- X fp32 [T,1024] -> bf16 into gate_in[T,2048] cols 0..1023 ----------------
__global__ void k_stage_x(const float4* __restrict__ X, unsigned short* __restrict__ gate_in, int n4) {
  int i = blockIdx.x * blockDim.x + threadIdx.x;
  if (i < n4) {
    int flat = i << 2;
    int row = flat >> 10, col = flat & 1023;
    float4 v = X[i];
    ushort4 o; o.x = f2bf(v.x); o.y = f2bf(v.y); o.z = f2bf(v.z); o.w = f2bf(v.w);
    *(ushort4*)(gate_in + (size_t)row * 2048 + col) = o;
  }
}

__global__ void k_concat_bias(const float* __restrict__ bk, const float* __restrict__ bv,
                              float* __restrict__ bkv) {
  int i = blockIdx.x * blockDim.x + threadIdx.x;
  if (i < 2048) bkv[i] = (i < 1024) ? bk[i] : bv[i - 1024];
}

// ---------------- KV fp32 [512,2048] -> Kn bf16 [512,1024] (normalized), Vt bf16 [1024,512] ----------------
__global__ void k_post_kv(const float4* __restrict__ KV, unsigned short* __restrict__ Kn,
                          unsigned short* __restrict__ Vt) {
  int row = blockIdx.x;   // 512
  int tid = threadIdx.x;  // 256
  const float4* r = KV + (size_t)row * 512;
  float4 k4 = r[tid];
  float4 v4 = r[256 + tid];
  float s = k4.x * k4.x + k4.y * k4.y + k4.z * k4.z + k4.w * k4.w;
  #pragma unroll
  for (int m = 32; m; m >>= 1) s += __shfl_xor(s, m, 64);
  __shared__ float red[4];
  if ((tid & 63) == 0) red[tid >> 6] = s;
  __syncthreads();
  float tot = red[0] + red[1] + red[2] + red[3];
  float inv = 1.0f / fmaxf(sqrtf(tot), 1e-12f);
  ushort4 o; o.x = f2bf(k4.x * inv); o.y = f2bf(k4.y * inv);
  o.z = f2bf(k4.z * inv); o.w = f2bf(k4.w * inv);
  *(ushort4*)(Kn + (size_t)row * 1024 + tid * 4) = o;
  int vc = tid * 4;
  Vt[(size_t)(vc + 0) * 512 + row] = f2bf(v4.x);
  Vt[(size_t)(vc + 1) * 512 + row] = f2bf(v4.y);
  Vt[(size_t)(vc + 2) * 512 + row] = f2bf(v4.z);
  Vt[(size_t)(vc + 3) * 512 + row] = f2bf(v4.w);
}

// ---------------- softmax with per-row temperature: w = softmax(S * alpha_row) ----------------
__global__ void k_softmax(const float4* __restrict__ S, const float* __restrict__ norm2,
                          unsigned short* __restrict__ W) {
  int tid = threadIdx.x;
  int wv = tid >> 6, lane = tid & 63;
  int row = blockIdx.x * 4 + wv;
  float alpha = 0.03125f * rsqrtf(fmaxf(norm2[row], 1e-24f));
  const float4* sr = S + (size_t)row * 128;
  float4 a = sr[lane], b = sr[64 + lane];
  a.x *= alpha; a.y *= alpha; a.z *= alpha; a.w *= alpha;
  b.x *= alpha; b.y *= alpha; b.z *= alpha; b.w *= alpha;
  float m = fmaxf(fmaxf(fmaxf(a.x, a.y), fmaxf(a.z, a.w)),
                  fmaxf(fmaxf(b.x, b.y), fmaxf(b.z, b.w)));
  #pragma unroll
  for (int o = 32; o; o >>= 1) m = fmaxf(m, __shfl_xor(m, o, 64));
  a.x = __expf(a.x - m); a.y = __expf(a.y - m); a.z = __expf(a.z - m); a.w = __expf(a.w - m);
  b.x = __expf(b.x - m); b.y = __expf(b.y - m); b.z = __expf(b.z - m); b.w = __expf(b.w - m);
  float s = a.x + a.y + a.z + a.w + b.x + b.y + b.z + b.w;
  #pragma unroll
  for (int o = 32; o; o >>= 1) s += __shfl_xor(s, o, 64);
  float inv = 1.0f / s;
  ushort4 oa, ob;
  oa.x = f2bf(a.x * inv); oa.y = f2bf(a.y * inv); oa.z = f2bf(a.z * inv); oa.w = f2bf(a.w * inv);
  ob.x = f2bf(b.x * inv); ob.y = f2bf(b.y * inv); ob.z = f2bf(b.z * inv); ob.w = f2bf(b.w * inv);
  ushort4* wr = (ushort4*)(W + (size_t)row * 512);
  wr[lane] = oa; wr[64 + lane] = ob;
}

// ---------------- old 128x128 GEMM (kept for the tiny KV GEMM only) ----------------
template <int MODE>
__global__ __launch_bounds__(256, 2) void k_gemm(
    const unsigned short* __restrict__ A, int lda,
    const unsigned short* __restrict__ B, int ldb,
    const float* __restrict__ bias, float scale,
    float* __restrict__ C, int ldc,
    unsigned short* __restrict__ Cb, int ldcb,
    float* __restrict__ Cnorm,
    int K) {
  __shared__ __align__(16) unsigned short As[128 * 64];
  __shared__ __align__(16) unsigned short Bs[128 * 64];
  const int tid = threadIdx.x;
  const int lane = tid & 63, w = tid >> 6;

  int mt = blockIdx.y, nt = blockIdx.x;
  const int m0 = mt * 128, n0 = nt * 128;

  const int srow = lane >> 3;
  const int schunk = (lane & 7) ^ srow;
  const unsigned short* gA = A + (size_t)(m0 + w * 8 + srow) * lda + schunk * 8;
  const unsigned short* gB = B + (size_t)(n0 + w * 8 + srow) * ldb + schunk * 8;
  unsigned short* lA = As + (w * 8) * 64;
  unsigned short* lB = Bs + (w * 8) * 64;

  f32x4 acc[4][4];
  f32x4 zero = {0.f, 0.f, 0.f, 0.f};
  #pragma unroll
  for (int i = 0; i < 4; ++i)
    #pragma unroll
    for (int j = 0; j < 4; ++j) acc[i][j] = zero;

  const int fr = lane & 15, q = lane >> 4;
  const int wr = (w >> 1) * 64, wc = (w & 1) * 64;

  for (int k0 = 0; k0 < K; k0 += 64) {
    #pragma unroll
    for (int i = 0; i < 4; ++i) {
      __builtin_amdgcn_global_load_lds(to_glb(gA + (size_t)i * 32 * lda + k0),
                                       to_lds(lA + i * 32 * 64), 16, 0, 0);
      __builtin_amdgcn_global_load_lds(to_glb(gB + (size_t)i * 32 * ldb + k0),
                                       to_lds(lB + i * 32 * 64), 16, 0, 0);
    }
    __syncthreads();
    #pragma unroll
    for (int ks = 0; ks < 2; ++ks) {
      bf16x8 af[4], bfr[4];
      const int p = (ks * 4 + q) ^ (lane & 7);
      #pragma unroll
      for (int mi = 0; mi < 4; ++mi) {
        af[mi] = *(const bf16x8*)(As + (wr + mi * 16 + fr) * 64 + p * 8);
        bfr[mi] = *(const bf16x8*)(Bs + (wc + mi * 16 + fr) * 64 + p * 8);
      }
      #pragma unroll
      for (int mi = 0; mi < 4; ++mi)
        #pragma unroll
        for (int ni = 0; ni < 4; ++ni)
          acc[mi][ni] = __builtin_amdgcn_mfma_f32_16x16x32_bf16(af[mi], bfr[ni], acc[mi][ni], 0, 0, 0);
    }
    __syncthreads();
  }

  #pragma unroll
  for (int ni = 0; ni < 4; ++ni) {
    const int gc = n0 + wc + ni * 16 + fr;
    const float bv = bias ? bias[gc] : 0.0f;
    #pragma unroll
    for (int mi = 0; mi < 4; ++mi) {
      #pragma unroll
      for (int r = 0; r < 4; ++r) {
        const int gr = m0 + wr + mi * 16 + q * 4 + r;
        float c = acc[mi][ni][r] * scale + bv;
        C[(size_t)gr * ldc + gc] = c;
      }
    }
  }
  (void)Cb; (void)ldcb; (void)Cnorm;
}

// ---------------- 256x256 8-phase GEMM (T2+T3+T4+T5), C[M,N] = A[M,K] * B^T ([N,K]) ----------------
// 8 waves (2M x 4N), BK=64, per-wave C = 128x64 as interleaved quadrants:
//   rows: qm*128 + wm*64 + mi*16, cols: qn*128 + wn*32 + ni*16.
// LDS 128 KiB: 2 buffers x (A[256][64] + B[256][64]) bf16, chunk-XOR swizzle
// (row r, logical k-chunk c stored at chunk c^(r&7)); staged via global_load_lds
// width-16 with pre-swizzled global source (linear LDS dest).
// Schedule per iteration (2 K-tiles t,t+1; buf0=even, buf1=odd):
//   ph1: rd A0,B0(buf0)        stage buf1.Ah1<-t+1   mfma quad(0,0)
//   ph2: rd B1(buf0)           stage buf0.Ah0<-t+2   mfma quad(0,1)
//   ph3: rd A1(buf0)           stage buf0.Bh0<-t+2   mfma quad(1,0)
//   ph4: (reuse regs)          stage buf0.Bh1<-t+2   mfma quad(1,1)
//   ph5..8: same on buf1, staging buf0.Ah1<-t+2 then buf1.{Ah0,Bh0,Bh1}<-t+3
// Uniform s_waitcnt vmcnt(10) at each phase end keeps 5 half-tile stages in
// flight; each phase's ds_read depends on the stage issued exactly 7 phases
// earlier, which vmcnt(10) pins. Tail stages clamp k0 (redundant valid loads)
// so the count stays exact. Never drains vmcnt to 0 inside the loop.
template <int MODE>
__global__ __launch_bounds__(512, 2) void k_gemm256(
    const unsigned short* __restrict__ A, int lda,
    const unsigned short* __restrict__ B, int ldb,
    const float* __restrict__ bias, float scale,
    float* __restrict__ C, int ldc,
    unsigned short* __restrict__ Cb, int ldcb,
    float* __restrict__ Cnorm,
    int K) {
  __shared__ __align__(16) unsigned short As[2 * 256 * 64];
  __shared__ __align__(16) unsigned short Bs[2 * 256 * 64];
  const int tid = threadIdx.x;
  const int lane = tid & 63, w = tid >> 6;
  const int wm = w >> 2, wn = w & 3;
  const int fr = lane & 15, q = lane >> 4;

  // XCD-aware tile remap (gridDim.y % 8 == 0 for all call sites)
  int mt, nt;
  {
    int f = blockIdx.y * gridDim.x + blockIdx.x;
    int NTg = gridDim.x, MTg = gridDim.y;
    if ((MTg & 7) == 0) {
      int xcd = f & 7;
      int j = f >> 3;
      nt = j % NTg;
      mt = (j / NTg) * 8 + xcd;
    } else {
      mt = blockIdx.y; nt = blockIdx.x;
    }
  }
  const int m0 = mt * 256, n0 = nt * 256;

  const int lr = lane >> 3;              // row within the wave's 8-row group
  const int lc = ((lane & 7) ^ lr) * 8;  // pre-swizzled source k-offset (elems)
  const int NT_ = K >> 6;                // number of 64-wide K-tiles
  const int NITER = NT_ >> 1;

  unsigned short* As0 = As;
  unsigned short* As1 = As + 256 * 64;
  unsigned short* Bs0 = Bs;
  unsigned short* Bs1 = Bs + 256 * 64;

  f32x4 acc[2][2][4][2];
  {
    f32x4 zero = {0.f, 0.f, 0.f, 0.f};
    #pragma unroll
    for (int a = 0; a < 2; ++a)
      #pragma unroll
      for (int b = 0; b < 2; ++b)
        #pragma unroll
        for (int c = 0; c < 4; ++c)
          #pragma unroll
          for (int d = 0; d < 2; ++d) acc[a][b][c][d] = zero;
  }

// stage one half-tile (128 rows x 64 cols): 2 x global_load_lds(16B) per thread
#define STG(g, ld, rbase, h, kt, L) do {                                        \
    int k0s = ((kt) < NT_ ? (kt) : (NT_ - 1)) * 64;                             \
    _Pragma("unroll")                                                           \
    for (int j = 0; j < 2; ++j) {                                               \
      __builtin_amdgcn_global_load_lds(                                         \
          to_glb((g) + (size_t)((rbase) + (h) * 128 + j * 64 + w * 8 + lr) *    \
                           (size_t)(ld) + k0s + lc),                            \
          to_lds((L) + ((h) * 128 + j * 64 + w * 8) * 64), 16, 0, 0);           \
    } } while (0)

#define RD_A(L, QM) do {                                                        \
    _Pragma("unroll")                                                           \
    for (int ks = 0; ks < 2; ++ks)                                              \
      _Pragma("unroll")                                                         \
      for (int mi = 0; mi < 4; ++mi)                                            \
        a_f[ks][mi] = *(const bf16x8*)((L) +                                    \
            ((QM) * 128 + wm * 64 + mi * 16 + fr) * 64 +                        \
            (((ks * 4 + q) ^ (fr & 7)) * 8));                                   \
  } while (0)

#define RD_B(L, QN, dst) do {                                                   \
    _Pragma("unroll")                                                           \
    for (int ks = 0; ks < 2; ++ks)                                              \
      _Pragma("unroll")                                                         \
      for (int ni = 0; ni < 2; ++ni)                                            \
        dst[ks][ni] = *(const bf16x8*)((L) +                                    \
            ((QN) * 128 + wn * 32 + ni * 16 + fr) * 64 +                        \
            (((ks * 4 + q) ^ (fr & 7)) * 8));                                   \
  } while (0)

#define MQ(QM, QN, bsrc) do {                                                   \
    _Pragma("unroll")                                                           \
    for (int ks = 0; ks < 2; ++ks)                                              \
      _Pragma("unroll")                                                         \
      for (int mi = 0; mi < 4; ++mi)                                            \
        _Pragma("unroll")                                                       \
        for (int ni = 0; ni < 2; ++ni)                                          \
          acc[QM][QN][mi][ni] = __builtin_amdgcn_mfma_f32_16x16x32_bf16(        \
              a_f[ks][mi], bsrc[ks][ni], acc[QM][QN][mi][ni], 0, 0, 0);         \
  } while (0)

#define BAR_MID() do {                                                          \
    __builtin_amdgcn_s_barrier();                                               \
    asm volatile("s_waitcnt lgkmcnt(0)" ::: "memory");                          \
    __builtin_amdgcn_sched_barrier(0);                                          \
    __builtin_amdgcn_s_setprio(1);                                              \
  } while (0)

#define BAR_END() do {                                                          \
    __builtin_amdgcn_s_setprio(0);                                              \
    asm volatile("s_waitcnt vmcnt(10)" ::: "memory");                           \
    __builtin_amdgcn_sched_barrier(0);                                          \
    __builtin_amdgcn_s_barrier();                                               \
    __builtin_amdgcn_sched_barrier(0);                                          \
  } while (0)

  // prologue: 7 half-tiles (tile0 full into buf0; tile1 Ah0,Bh0,Bh1 into buf1)
  STG(A, lda, m0, 0, 0, As0);  // p1 buf0.Ah0
  STG(B, ldb, n0, 0, 0, Bs0);  // p2 buf0.Bh0
  STG(B, ldb, n0, 1, 0, Bs0);  // p3 buf0.Bh1
  STG(A, lda, m0, 1, 0, As0);  // p4 buf0.Ah1
  STG(A, lda, m0, 0, 1, As1);  // p5 buf1.Ah0
  STG(B, ldb, n0, 0, 1, Bs1);  // p6 buf1.Bh0
  STG(B, ldb, n0, 1, 1, Bs1);  // p7 buf1.Bh1
  asm volatile("s_waitcnt vmcnt(10)" ::: "memory");
  __builtin_amdgcn_sched_barrier(0);
  __builtin_amdgcn_s_barrier();
  __builtin_amdgcn_sched_barrier(0);

  bf16x8 a_f[2][4], b0[2][2], b1[2][2];

  for (int it = 0; it < NITER; ++it) {
    const int t = it * 2;
    // ph1
    RD_A(As0, 0); RD_B(Bs0, 0, b0);
    STG(A, lda, m0, 1, t + 1, As1);      // buf1.Ah1 <- t+1 (read ph7)
    BAR_MID(); MQ(0, 0, b0); BAR_END();
    // ph2
    RD_B(Bs0, 1, b1);
    STG(A, lda, m0, 0, t + 2, As0);      // buf0.Ah0 <- t+2
    BAR_MID(); MQ(0, 1, b1); BAR_END();
    // ph3
    RD_A(As0, 1);
    STG(B, ldb, n0, 0, t + 2, Bs0);      // buf0.Bh0 <- t+2
    BAR_MID(); MQ(1, 0, b0); BAR_END();
    // ph4
    STG(B, ldb, n0, 1, t + 2, Bs0);      // buf0.Bh1 <- t+2
    BAR_MID(); MQ(1, 1, b1); BAR_END();
    // ph5
    RD_A(As1, 0); RD_B(Bs1, 0, b0);
    STG(A, lda, m0, 1, t + 2, As0);      // buf0.Ah1 <- t+2
    BAR_MID(); MQ(0, 0, b0); BAR_END();
    // ph6
    RD_B(Bs1, 1, b1);
    STG(A, lda, m0, 0, t + 3, As1);      // buf1.Ah0 <- t+3
    BAR_MID(); MQ(0, 1, b1); BAR_END();
    // ph7
    RD_A(As1, 1);
    STG(B, ldb, n0, 0, t + 3, Bs1);      // buf1.Bh0 <- t+3
    BAR_MID(); MQ(1, 0, b0); BAR_END();
    // ph8
    STG(B, ldb, n0, 1, t + 3, Bs1);      // buf1.Bh1 <- t+3
    BAR_MID(); MQ(1, 1, b1); BAR_END();
  }

  // drain pending LDS-DMA before workgroup teardown / epilogue
  asm volatile("s_waitcnt vmcnt(0)" ::: "memory");
  __builtin_amdgcn_sched_barrier(0);

#undef STG
#undef RD_A
#undef RD_B
#undef MQ
#undef BAR_MID
#undef BAR_END

  if (MODE == 1) {
    // bf16 store + per-row sum-of-squares accumulation (deferred l2-norm)
    #pragma unroll
    for (int qm = 0; qm < 2; ++qm)
      #pragma unroll
      for (int mi = 0; mi < 4; ++mi) {
        float s2[4] = {0.f, 0.f, 0.f, 0.f};
        #pragma unroll
        for (int qn = 0; qn < 2; ++qn)
          #pragma unroll
          for (int ni = 0; ni < 2; ++ni) {
            const int gc = n0 + qn * 128 + wn * 32 + ni * 16 + fr;
            const float bv = bias[gc];
            #pragma unroll
            for (int r = 0; r < 4; ++r) {
              const int gr = m0 + qm * 128 + wm * 64 + mi * 16 + q * 4 + r;
              float c = acc[qm][qn][mi][ni][r] + bv;
              Cb[(size_t)gr * ldcb + gc] = f2bf(c);
              s2[r] += c * c;
            }
          }
        #pragma unroll
        for (int r = 0; r < 4; ++r) {
          float v = s2[r];
          v += __shfl_xor(v, 1, 64);
          v += __shfl_xor(v, 2, 64);
          v += __shfl_xor(v, 4, 64);
          v += __shfl_xor(v, 8, 64);
          if (fr == 0)
            atomicAdd(Cnorm + (m0 + qm * 128 + wm * 64 + mi * 16 + q * 4 + r), v);
        }
      }
  } else {
    #pragma unroll
    for (int qm = 0; qm < 2; ++qm)
      #pragma unroll
      for (int qn = 0; qn < 2; ++qn)
        #pragma unroll
        for (int ni = 0; ni < 2; ++ni) {
          const int gc = n0 + qn * 128 + wn * 32 + ni * 16 + fr;
          const float bv = bias ? bias[gc] : 0.0f;
          #pragma unroll
          for (int mi = 0; mi < 4; ++mi)
            #pragma unroll
            for (int r = 0; r < 4; ++r) {
              const int gr = m0 + qm * 128 + wm * 64 + mi * 16 + q * 4 + r;
              float c = acc[qm][qn][mi][ni][r] * scale + bv;
              if (MODE == 0) {
                C[(size_t)gr * ldc + gc] = c;
              } else if (MODE == 2) {
                Cb[(size_t)gr * ldcb + gc] = f2bf(c);
              } else {  // MODE 3: fused sigmoid gate
                float g = 1.0f / (1.0f + __expf(-c));
                float x = bf2f(Cb[(size_t)gr * ldcb + gc]);
                float rr = bf2f(Cb[(size_t)gr * ldcb + 1024 + gc]);
                C[(size_t)gr * ldc + gc] = g * x + (1.0f - g) * rr;
              }
            }
        }
  }
}

extern "C" void kernel_launch(void* const* d_in, const int* in_sizes, int n_in,
                              void* d_out, int out_size, void* d_ws, size_t ws_size,
                              hipStream_t stream) {
  const float* X   = (const float*)d_in[0];
  const float* mem = (const float*)d_in[1];
  const float* Wq  = (const float*)d_in[2];
  const float* bq  = (const float*)d_in[3];
  const float* Wk  = (const float*)d_in[4];
  const float* bk  = (const float*)d_in[5];
  const float* Wv  = (const float*)d_in[6];
  const float* bv  = (const float*)d_in[7];
  const float* Wg  = (const float*)d_in[8];
  const float* bg  = (const float*)d_in[9];
  float* out = (float*)d_out;

  const int T = 32768, D = 1024, NS = 512;

  char* p = (char*)d_ws;
  auto alloc = [&](size_t b) { char* r = p; p += (b + 255) & ~(size_t)255; return r; };
  unsigned short* WqT    = (unsigned short*)alloc((size_t)D * D * 2);
  unsigned short* WkvT   = (unsigned short*)alloc((size_t)2 * D * D * 2);
  unsigned short* WgT    = (unsigned short*)alloc((size_t)D * 2 * D * 2);
  unsigned short* memb   = (unsigned short*)alloc((size_t)NS * D * 2);
  float*          bkv    = (float*)alloc((size_t)2 * D * 4);
  float*          KV     = (float*)alloc((size_t)NS * 2 * D * 4);
  unsigned short* Kn     = (unsigned short*)alloc((size_t)NS * D * 2);
  unsigned short* Vt     = (unsigned short*)alloc((size_t)D * NS * 2);
  unsigned short* gatein = (unsigned short*)alloc((size_t)T * 2 * D * 2);  // [T,2048]: X | R
  unsigned short* Qb     = (unsigned short*)alloc((size_t)T * D * 2);      // Q bf16 (unnormalized)
  unsigned short* Wsm    = (unsigned short*)alloc((size_t)T * NS * 2);     // softmax weights bf16
  float*          S      = (float*)alloc((size_t)T * NS * 4);              // scores fp32
  float*          norm2  = (float*)alloc((size_t)T * 4);                   // ||Q_row||^2

  hipMemsetAsync(norm2, 0, (size_t)T * 4, stream);

  // --- prep: weight transposes to [N,K] bf16, converts ---
  k_transpose_bf16<<<dim3(32, 32), dim3(32, 8), 0, stream>>>(Wq, WqT, D, D);
  k_transpose_bf16<<<dim3(32, 32), dim3(32, 8), 0, stream>>>(Wk, WkvT, D, D);
  k_transpose_bf16<<<dim3(32, 32), dim3(32, 8), 0, stream>>>(Wv, WkvT + (size_t)D * D, D, D);
  k_transpose_bf16<<<dim3(32, 64), dim3(32, 8), 0, stream>>>(Wg, WgT, 2 * D, D);
  k_convert_bf16<<<512, 256, 0, stream>>>((const float4*)mem, (ushort4*)memb, NS * D / 4);
  k_concat_bias<<<8, 256, 0, stream>>>(bk, bv, bkv);
  k_stage_x<<<T * D / 4 / 256, 256, 0, stream>>>((const float4*)X, gatein, T * D / 4);

  // --- K,V: [512,2048] = memb @ [Wk|Wv] + [bk|bv] (tiny: old 128^2 kernel) ---
  k_gemm<0><<<dim3(2 * D / 128, NS / 128), 256, 0, stream>>>(
      memb, D, WkvT, D, bkv, 1.0f, KV, 2 * D, nullptr, 0, nullptr, D);
  k_post_kv<<<NS, 256, 0, stream>>>((const float4*)KV, Kn, Vt);

  // --- Q = X @ Wq + bq -> bf16 Qb + row norms (normalization deferred to softmax) ---
  k_gemm256<1><<<dim3(D / 256, T / 256), 512, 0, stream>>>(
      gatein, 2 * D, WqT, D, bq, 1.0f, nullptr, 0, Qb, D, norm2, D);

  // --- scores_raw = Q @ Kn^T (temperature applied in softmax) ---
  k_gemm256<0><<<dim3(NS / 256, T / 256), 512, 0, stream>>>(
      Qb, D, Kn, D, nullptr, 1.0f, S, NS, nullptr, 0, nullptr, D);
  k_softmax<<<T / 4, 256, 0, stream>>>((const float4*)S, norm2, Wsm);

  // --- R = w @ V -> bf16 into gate_in cols 1024.. ---
  k_gemm256<2><<<dim3(D / 256, T / 256), 512, 0, stream>>>(
      Wsm, NS, Vt, NS, nullptr, 1.0f, nullptr, 0, gatein + D, 2 * D, nullptr, NS);

  // --- gate: g = sigmoid([X,R] @ Wg + bg); out = g*x + (1-g)*r ---
  k_gemm256<3><<<dim3(D / 256, T / 256), 512, 0, stream>>>(
      gatein, 2 * D, WgT, 2 * D, bg, 1.0f, out, D, gatein, 2 * D, nullptr, 2 * D);

  (void)in_sizes; (void)n_in; (void)out_size; (void)ws_size;
}

// Round 2
// 662.989 us; speedup vs baseline: 1.0065x; 1.0065x over previous
//
#include <hip/hip_runtime.h>
#include <cstdint>

typedef __attribute__((ext_vector_type(8))) __bf16 bf16x8;
typedef __attribute__((ext_vector_type(4))) float f32x4;

__device__ __forceinline__ unsigned short f2bf(float f) {
  unsigned u = __float_as_uint(f);
  unsigned r = (u + 0x7FFFu + ((u >> 16) & 1u)) >> 16;  // RNE
  return (unsigned short)r;
}
__device__ __forceinline__ float bf2f(unsigned short u) {
  return __uint_as_float(((unsigned)u) << 16);
}

__device__ __forceinline__ __attribute__((address_space(3))) void* to_lds(void* p) {
  return (__attribute__((address_space(3))) void*)p;
}
__device__ __forceinline__ const __attribute__((address_space(1))) void* to_glb(const void* p) {
  return (const __attribute__((address_space(1))) void*)p;
}

// ---------------- transpose: fp32 in[R,C] -> bf16 out[C,R] ----------------
__global__ void k_transpose_bf16(const float* __restrict__ in, unsigned short* __restrict__ out,
                                 int R, int C) {
  __shared__ float tile[32][33];
  int c0 = blockIdx.x * 32, r0 = blockIdx.y * 32;
  int tx = threadIdx.x, ty = threadIdx.y;  // block (32,8)
  #pragma unroll
  for (int i = 0; i < 32; i += 8)
    tile[ty + i][tx] = in[(size_t)(r0 + ty + i) * C + c0 + tx];
  __syncthreads();
  #pragma unroll
  for (int i = 0; i < 32; i += 8)
    out[(size_t)(c0 + ty + i) * R + r0 + tx] = f2bf(tile[tx][ty + i]);
}

// ---------------- fp32 -> bf16 contiguous ----------------
__global__ void k_convert_bf16(const float4* __restrict__ in, ushort4* __restrict__ out, int n4) {
  int i = blockIdx.x * blockDim.x + threadIdx.x;
  if (i < n4) {
    float4 v = in[i];
    ushort4 o; o.x = f2bf(v.x); o.y = f2bf(v.y); o.z = f2bf(v.z); o.w = f2bf(v.w);
    out[i] = o;
  }
}

// ---------------- X fp32 [T,1024] -> bf16 into gate_in[T,2048] cols 0..1023 ----------------
__global__ void k_stage_x(const float4* __restrict__ X, unsigned short* __restrict__ gate_in, int n4) {
  int i = blockIdx.x * blockDim.x + threadIdx.x;
  if (i < n4) {
    int flat = i << 2;
    int row = flat >> 10, col = flat & 1023;
    float4 v = X[i];
    ushort4 o; o.x = f2bf(v.x); o.y = f2bf(v.y); o.z = f2bf(v.z); o.w = f2bf(v.w);
    *(ushort4*)(gate_in + (size_t)row * 2048 + col) = o;
  }
}

__global__ void k_concat_bias(const float* __restrict__ bk, const float* __restrict__ bv,
                              float* __restrict__ bkv) {
  int i = blockIdx.x * blockDim.x + threadIdx.x;
  if (i < 2048) bkv[i] = (i < 1024) ? bk[i] : bv[i - 1024];
}

// ---------------- KV fp32 [512,2048] -> Kn bf16 [512,1024] (normalized), Vt bf16 [1024,512] ----------------
__global__ void k_post_kv(const float4* __restrict__ KV, unsigned short* __restrict__ Kn,
                          unsigned short* __restrict__ Vt) {
  int row = blockIdx.x;   // 512
  int tid = threadIdx.x;  // 256
  const float4* r = KV + (size_t)row * 512;
  float4 k4 = r[tid];
  float4 v4 = r[256 + tid];
  float s = k4.x * k4.x + k4.y * k4.y + k4.z * k4.z + k4.w * k4.w;
  #pragma unroll
  for (int m = 32; m; m >>= 1) s += __shfl_xor(s, m, 64);
  __shared__ float red[4];
  if ((tid & 63) == 0) red[tid >> 6] = s;
  __syncthreads();
  float tot = red[0] + red[1] + red[2] + red[3];
  float inv = 1.0f / fmaxf(sqrtf(tot), 1e-12f);
  ushort4 o; o.x = f2bf(k4.x * inv); o.y = f2bf(k4.y * inv);
  o.z = f2bf(k4.z * inv); o.w = f2bf(k4.w * inv);
  *(ushort4*)(Kn + (size_t)row * 1024 + tid * 4) = o;
  int vc = tid * 4;
  Vt[(size_t)(vc + 0) * 512 + row] = f2bf(v4.x);
  Vt[(size_t)(vc + 1) * 512 + row] = f2bf(v4.y);
  Vt[(size_t)(vc + 2) * 512 + row] = f2bf(v4.z);
  Vt[(size_t)(vc + 3) * 512 + row] = f2bf(v4.w);
}

// ---------------- softmax with per-row temperature: w = softmax(S * alpha_row) ----------------
__global__ void k_softmax(const float4* __restrict__ S, const float* __restrict__ norm2,
                          unsigned short* __restrict__ W) {
  int tid = threadIdx.x;
  int wv = tid >> 6, lane = tid & 63;
  int row = blockIdx.x * 4 + wv;
  float alpha = 0.03125f * rsqrtf(fmaxf(norm2[row], 1e-24f));
  const float4* sr = S + (size_t)row * 128;
  float4 a = sr[lane], b = sr[64 + lane];
  a.x *= alpha; a.y *= alpha; a.z *= alpha; a.w *= alpha;
  b.x *= alpha; b.y *= alpha; b.z *= alpha; b.w *= alpha;
  float m = fmaxf(fmaxf(fmaxf(a.x, a.y), fmaxf(a.z, a.w)),
                  fmaxf(fmaxf(b.x, b.y), fmaxf(b.z, b.w)));
  #pragma unroll
  for (int o = 32; o; o >>= 1) m = fmaxf(m, __shfl_xor(m, o, 64));
  a.x = __expf(a.x - m); a.y = __expf(a.y - m); a.z = __expf(a.z - m); a.w = __expf(a.w - m);
  b.x = __expf(b.x - m); b.y = __expf(b.y - m); b.z = __expf(b.z - m); b.w = __expf(b.w - m);
  float s = a.x + a.y + a.z + a.w + b.x + b.y + b.z + b.w;
  #pragma unroll
  for (int o = 32; o; o >>= 1) s += __shfl_xor(s, o, 64);
  float inv = 1.0f / s;
  ushort4 oa, ob;
  oa.x = f2bf(a.x * inv); oa.y = f2bf(a.y * inv); oa.z = f2bf(a.z * inv); oa.w = f2bf(a.w * inv);
  ob.x = f2bf(b.x * inv); ob.y = f2bf(b.y * inv); ob.z = f2bf(b.z * inv); ob.w = f2bf(b.w * inv);
  ushort4* wr = (ushort4*)(W + (size_t)row * 512);
  wr[lane] = oa; wr[64 + lane] = ob;
}

// ---------------- old 128x128 GEMM (kept for the tiny KV GEMM only) ----------------
template <int MODE>
__global__ __launch_bounds__(256, 2) void k_gemm(
    const unsigned short* __restrict__ A, int lda,
    const unsigned short* __restrict__ B, int ldb,
    const float* __restrict__ bias, float scale,
    float* __restrict__ C, int ldc,
    unsigned short* __restrict__ Cb, int ldcb,
    float* __restrict__ Cnorm,
    int K) {
  __shared__ __align__(16) unsigned short As[128 * 64];
  __shared__ __align__(16) unsigned short Bs[128 * 64];
  const int tid = threadIdx.x;
  const int lane = tid & 63, w = tid >> 6;

  int mt = blockIdx.y, nt = blockIdx.x;
  const int m0 = mt * 128, n0 = nt * 128;

  const int srow = lane >> 3;
  const int schunk = (lane & 7) ^ srow;
  const unsigned short* gA = A + (size_t)(m0 + w * 8 + srow) * lda + schunk * 8;
  const unsigned short* gB = B + (size_t)(n0 + w * 8 + srow) * ldb + schunk * 8;
  unsigned short* lA = As + (w * 8) * 64;
  unsigned short* lB = Bs + (w * 8) * 64;

  f32x4 acc[4][4];
  f32x4 zero = {0.f, 0.f, 0.f, 0.f};
  #pragma unroll
  for (int i = 0; i < 4; ++i)
    #pragma unroll
    for (int j = 0; j < 4; ++j) acc[i][j] = zero;

  const int fr = lane & 15, q = lane >> 4;
  const int wr = (w >> 1) * 64, wc = (w & 1) * 64;

  for (int k0 = 0; k0 < K; k0 += 64) {
    #pragma unroll
    for (int i = 0; i < 4; ++i) {
      __builtin_amdgcn_global_load_lds(to_glb(gA + (size_t)i * 32 * lda + k0),
                                       to_lds(lA + i * 32 * 64), 16, 0, 0);
      __builtin_amdgcn_global_load_lds(to_glb(gB + (size_t)i * 32 * ldb + k0),
                                       to_lds(lB + i * 32 * 64), 16, 0, 0);
    }
    __syncthreads();
    #pragma unroll
    for (int ks = 0; ks < 2; ++ks) {
      bf16x8 af[4], bfr[4];
      const int p = (ks * 4 + q) ^ (lane & 7);
      #pragma unroll
      for (int mi = 0; mi < 4; ++mi) {
        af[mi] = *(const bf16x8*)(As + (wr + mi * 16 + fr) * 64 + p * 8);
        bfr[mi] = *(const bf16x8*)(Bs + (wc + mi * 16 + fr) * 64 + p * 8);
      }
      #pragma unroll
      for (int mi = 0; mi < 4; ++mi)
        #pragma unroll
        for (int ni = 0; ni < 4; ++ni)
          acc[mi][ni] = __builtin_amdgcn_mfma_f32_16x16x32_bf16(af[mi], bfr[ni], acc[mi][ni], 0, 0, 0);
    }
    __syncthreads();
  }

  #pragma unroll
  for (int ni = 0; ni < 4; ++ni) {
    const int gc = n0 + wc + ni * 16 + fr;
    const float bv = bias ? bias[gc] : 0.0f;
    #pragma unroll
    for (int mi = 0; mi < 4; ++mi) {
      #pragma unroll
      for (int r = 0; r < 4; ++r) {
        const int gr = m0 + wr + mi * 16 + q * 4 + r;
        float c = acc[mi][ni][r] * scale + bv;
        C[(size_t)gr * ldc + gc] = c;
      }
    }
  }
  (void)Cb; (void)ldcb; (void)Cnorm;
}

// ---------------- 256x256 8-phase GEMM (T2+T3+T4+T5), C[M,N] = A[M,K] * B^T ([N,K]) ----------------
// 8 waves (2M x 4N), BK=64, per-wave C = 128x64 as interleaved quadrants:
//   rows: qm*128 + wm*64 + mi*16, cols: qn*128 + wn*32 + ni*16.
// LDS 128 KiB: 2 buffers x (A[256][64] + B[256][64]) bf16, chunk-XOR swizzle
// (row r, logical k-chunk c stored at chunk c^(r&7)); staged via global_load_lds
// width-16 with pre-swizzled global source (linear LDS dest).
// Schedule per iteration (2 K-tiles t,t+1; buf0=even, buf1=odd):
//   ph1: rd A0,B0(buf0)        stage buf1.Ah1<-t+1   mfma quad(0,0)
//   ph2: rd B1(buf0)           stage buf0.Ah0<-t+2   mfma quad(0,1)
//   ph3: rd A1(buf0)           stage buf0.Bh0<-t+2   mfma quad(1,0)
//   ph4: (reuse regs)          stage buf0.Bh1<-t+2   mfma quad(1,1)   [vmcnt(6)]
//   ph5..8: same on buf1, staging buf0.Ah1<-t+2 then buf1.{Ah0,Bh0,Bh1}<-t+3
//                                                                    [vmcnt(6) at ph8]
// T4 (counted vmcnt): waits ONLY at ph4/ph8 ends, N = 2 loads x 3 half-tiles = 6.
// Dependency check: newest stage needed by ph5..7 reads is ph1's (buf1.Ah1, read
// ph7) -> pinned by ph4's vmcnt(6) (last 3 in flight = ph2,3,4). Newest needed
// by next-iter ph1..3 is ph5's (buf0.Ah1, read next ph3) -> pinned by ph8's
// vmcnt(6) (last 3 = ph6,7,8). Tail stages clamp k0 (redundant valid loads) so
// the accounting stays exact. Never drains vmcnt to 0 inside the loop.
template <int MODE>
__global__ __launch_bounds__(512, 2) void k_gemm256(
    const unsigned short* __restrict__ A, int lda,
    const unsigned short* __restrict__ B, int ldb,
    const float* __restrict__ bias, float scale,
    float* __restrict__ C, int ldc,
    unsigned short* __restrict__ Cb, int ldcb,
    float* __restrict__ Cnorm,
    int K) {
  __shared__ __align__(16) unsigned short As[2 * 256 * 64];
  __shared__ __align__(16) unsigned short Bs[2 * 256 * 64];
  const int tid = threadIdx.x;
  const int lane = tid & 63, w = tid >> 6;
  const int wm = w >> 2, wn = w & 3;
  const int fr = lane & 15, q = lane >> 4;

  // XCD-aware tile remap (gridDim.y % 8 == 0 for all call sites)
  int mt, nt;
  {
    int f = blockIdx.y * gridDim.x + blockIdx.x;
    int NTg = gridDim.x, MTg = gridDim.y;
    if ((MTg & 7) == 0) {
      int xcd = f & 7;
      int j = f >> 3;
      nt = j % NTg;
      mt = (j / NTg) * 8 + xcd;
    } else {
      mt = blockIdx.y; nt = blockIdx.x;
    }
  }
  const int m0 = mt * 256, n0 = nt * 256;

  const int lr = lane >> 3;              // row within the wave's 8-row group
  const int lc = ((lane & 7) ^ lr) * 8;  // pre-swizzled source k-offset (elems)
  const int NT_ = K >> 6;                // number of 64-wide K-tiles
  const int NITER = NT_ >> 1;

  unsigned short* As0 = As;
  unsigned short* As1 = As + 256 * 64;
  unsigned short* Bs0 = Bs;
  unsigned short* Bs1 = Bs + 256 * 64;

  f32x4 acc[2][2][4][2];
  {
    f32x4 zero = {0.f, 0.f, 0.f, 0.f};
    #pragma unroll
    for (int a = 0; a < 2; ++a)
      #pragma unroll
      for (int b = 0; b < 2; ++b)
        #pragma unroll
        for (int c = 0; c < 4; ++c)
          #pragma unroll
          for (int d = 0; d < 2; ++d) acc[a][b][c][d] = zero;
  }

// stage one half-tile (128 rows x 64 cols): 2 x global_load_lds(16B) per thread
#define STG(g, ld, rbase, h, kt, L) do {                                        \
    int k0s = ((kt) < NT_ ? (kt) : (NT_ - 1)) * 64;                             \
    _Pragma("unroll")                                                           \
    for (int j = 0; j < 2; ++j) {                                               \
      __builtin_amdgcn_global_load_lds(                                         \
          to_glb((g) + (size_t)((rbase) + (h) * 128 + j * 64 + w * 8 + lr) *    \
                           (size_t)(ld) + k0s + lc),                            \
          to_lds((L) + ((h) * 128 + j * 64 + w * 8) * 64), 16, 0, 0);           \
    } } while (0)

#define RD_A(L, QM) do {                                                        \
    _Pragma("unroll")                                                           \
    for (int ks = 0; ks < 2; ++ks)                                              \
      _Pragma("unroll")                                                         \
      for (int mi = 0; mi < 4; ++mi)                                            \
        a_f[ks][mi] = *(const bf16x8*)((L) +                                    \
            ((QM) * 128 + wm * 64 + mi * 16 + fr) * 64 +                        \
            (((ks * 4 + q) ^ (fr & 7)) * 8));                                   \
  } while (0)

#define RD_B(L, QN, dst) do {                                                   \
    _Pragma("unroll")                                                           \
    for (int ks = 0; ks < 2; ++ks)                                              \
      _Pragma("unroll")                                                         \
      for (int ni = 0; ni < 2; ++ni)                                            \
        dst[ks][ni] = *(const bf16x8*)((L) +                                    \
            ((QN) * 128 + wn * 32 + ni * 16 + fr) * 64 +                        \
            (((ks * 4 + q) ^ (fr & 7)) * 8));                                   \
  } while (0)

#define MQ(QM, QN, bsrc) do {                                                   \
    _Pragma("unroll")                                                           \
    for (int ks = 0; ks < 2; ++ks)                                              \
      _Pragma("unroll")                                                         \
      for (int mi = 0; mi < 4; ++mi)                                            \
        _Pragma("unroll")                                                       \
        for (int ni = 0; ni < 2; ++ni)                                          \
          acc[QM][QN][mi][ni] = __builtin_amdgcn_mfma_f32_16x16x32_bf16(        \
              a_f[ks][mi], bsrc[ks][ni], acc[QM][QN][mi][ni], 0, 0, 0);         \
  } while (0)

#define BAR_MID() do {                                                          \
    __builtin_amdgcn_s_barrier();                                               \
    asm volatile("s_waitcnt lgkmcnt(0)" ::: "memory");                          \
    __builtin_amdgcn_sched_barrier(0);                                          \
    __builtin_amdgcn_s_setprio(1);                                              \
  } while (0)

// phase end without vmem wait (T4: loads stay in flight across barriers)
#define BAR_END() do {                                                          \
    __builtin_amdgcn_s_setprio(0);                                              \
    __builtin_amdgcn_s_barrier();                                               \
  } while (0)

// phase end WITH counted vmem wait (only ph4 / ph8)
#define BAR_END_VM() do {                                                       \
    __builtin_amdgcn_s_setprio(0);                                              \
    asm volatile("s_waitcnt vmcnt(6)" ::: "memory");                            \
    __builtin_amdgcn_s_barrier();                                               \
  } while (0)

  // prologue: 7 half-tiles (tile0 full into buf0; tile1 Ah0,Bh0,Bh1 into buf1);
  // vmcnt(6) pins stages 1..4 (= all of buf0) before the ph1..ph3 reads.
  STG(A, lda, m0, 0, 0, As0);  // s1 buf0.Ah0
  STG(B, ldb, n0, 0, 0, Bs0);  // s2 buf0.Bh0
  STG(B, ldb, n0, 1, 0, Bs0);  // s3 buf0.Bh1
  STG(A, lda, m0, 1, 0, As0);  // s4 buf0.Ah1
  STG(A, lda, m0, 0, 1, As1);  // s5 buf1.Ah0
  STG(B, ldb, n0, 0, 1, Bs1);  // s6 buf1.Bh0
  STG(B, ldb, n0, 1, 1, Bs1);  // s7 buf1.Bh1
  asm volatile("s_waitcnt vmcnt(6)" ::: "memory");
  __builtin_amdgcn_s_barrier();

  bf16x8 a_f[2][4], b0[2][2], b1[2][2];

  for (int it = 0; it < NITER; ++it) {
    const int t = it * 2;
    // ph1
    RD_A(As0, 0); RD_B(Bs0, 0, b0);
    STG(A, lda, m0, 1, t + 1, As1);      // buf1.Ah1 <- t+1 (read ph7)
    BAR_MID(); MQ(0, 0, b0); BAR_END();
    // ph2
    RD_B(Bs0, 1, b1);
    STG(A, lda, m0, 0, t + 2, As0);      // buf0.Ah0 <- t+2
    BAR_MID(); MQ(0, 1, b1); BAR_END();
    // ph3
    RD_A(As0, 1);
    STG(B, ldb, n0, 0, t + 2, Bs0);      // buf0.Bh0 <- t+2
    BAR_MID(); MQ(1, 0, b0); BAR_END();
    // ph4
    STG(B, ldb, n0, 1, t + 2, Bs0);      // buf0.Bh1 <- t+2
    BAR_MID(); MQ(1, 1, b1); BAR_END_VM();
    // ph5
    RD_A(As1, 0); RD_B(Bs1, 0, b0);
    STG(A, lda, m0, 1, t + 2, As0);      // buf0.Ah1 <- t+2
    BAR_MID(); MQ(0, 0, b0); BAR_END();
    // ph6
    RD_B(Bs1, 1, b1);
    STG(A, lda, m0, 0, t + 3, As1);      // buf1.Ah0 <- t+3
    BAR_MID(); MQ(0, 1, b1); BAR_END();
    // ph7
    RD_A(As1, 1);
    STG(B, ldb, n0, 0, t + 3, Bs1);      // buf1.Bh0 <- t+3
    BAR_MID(); MQ(1, 0, b0); BAR_END();
    // ph8
    STG(B, ldb, n0, 1, t + 3, Bs1);      // buf1.Bh1 <- t+3
    BAR_MID(); MQ(1, 1, b1); BAR_END_VM();
  }

  // drain pending LDS-DMA (only the clamped redundant tail stages remain)
  asm volatile("s_waitcnt vmcnt(0)" ::: "memory");
  __builtin_amdgcn_sched_barrier(0);

#undef STG
#undef RD_A
#undef RD_B
#undef MQ
#undef BAR_MID
#undef BAR_END
#undef BAR_END_VM

  if (MODE == 1) {
    // bf16 store + per-row sum-of-squares accumulation (deferred l2-norm)
    #pragma unroll
    for (int qm = 0; qm < 2; ++qm)
      #pragma unroll
      for (int mi = 0; mi < 4; ++mi) {
        float s2[4] = {0.f, 0.f, 0.f, 0.f};
        #pragma unroll
        for (int qn = 0; qn < 2; ++qn)
          #pragma unroll
          for (int ni = 0; ni < 2; ++ni) {
            const int gc = n0 + qn * 128 + wn * 32 + ni * 16 + fr;
            const float bv = bias[gc];
            #pragma unroll
            for (int r = 0; r < 4; ++r) {
              const int gr = m0 + qm * 128 + wm * 64 + mi * 16 + q * 4 + r;
              float c = acc[qm][qn][mi][ni][r] + bv;
              Cb[(size_t)gr * ldcb + gc] = f2bf(c);
              s2[r] += c * c;
            }
          }
        #pragma unroll
        for (int r = 0; r < 4; ++r) {
          float v = s2[r];
          v += __shfl_xor(v, 1, 64);
          v += __shfl_xor(v, 2, 64);
          v += __shfl_xor(v, 4, 64);
          v += __shfl_xor(v, 8, 64);
          if (fr == 0)
            atomicAdd(Cnorm + (m0 + qm * 128 + wm * 64 + mi * 16 + q * 4 + r), v);
        }
      }
  } else {
    #pragma unroll
    for (int qm = 0; qm < 2; ++qm)
      #pragma unroll
      for (int qn = 0; qn < 2; ++qn)
        #pragma unroll
        for (int ni = 0; ni < 2; ++ni) {
          const int gc = n0 + qn * 128 + wn * 32 + ni * 16 + fr;
          const float bv = bias ? bias[gc] : 0.0f;
          #pragma unroll
          for (int mi = 0; mi < 4; ++mi)
            #pragma unroll
            for (int r = 0; r < 4; ++r) {
              const int gr = m0 + qm * 128 + wm * 64 + mi * 16 + q * 4 + r;
              float c = acc[qm][qn][mi][ni][r] * scale + bv;
              if (MODE == 0) {
                C[(size_t)gr * ldc + gc] = c;
              } else if (MODE == 2) {
                Cb[(size_t)gr * ldcb + gc] = f2bf(c);
              } else {  // MODE 3: fused sigmoid gate
                float g = 1.0f / (1.0f + __expf(-c));
                float x = bf2f(Cb[(size_t)gr * ldcb + gc]);
                float rr = bf2f(Cb[(size_t)gr * ldcb + 1024 + gc]);
                C[(size_t)gr * ldc + gc] = g * x + (1.0f - g) * rr;
              }
            }
        }
  }
}

extern "C" void kernel_launch(void* const* d_in, const int* in_sizes, int n_in,
                              void* d_out, int out_size, void* d_ws, size_t ws_size,
                              hipStream_t stream) {
  const float* X   = (const float*)d_in[0];
  const float* mem = (const float*)d_in[1];
  const float* Wq  = (const float*)d_in[2];
  const float* bq  = (const float*)d_in[3];
  const float* Wk  = (const float*)d_in[4];
  const float* bk  = (const float*)d_in[5];
  const float* Wv  = (const float*)d_in[6];
  const float* bv  = (const float*)d_in[7];
  const float* Wg  = (const float*)d_in[8];
  const float* bg  = (const float*)d_in[9];
  float* out = (float*)d_out;

  const int T = 32768, D = 1024, NS = 512;

  char* p = (char*)d_ws;
  auto alloc = [&](size_t b) { char* r = p; p += (b + 255) & ~(size_t)255; return r; };
  unsigned short* WqT    = (unsigned short*)alloc((size_t)D * D * 2);
  unsigned short* WkvT   = (unsigned short*)alloc((size_t)2 * D * D * 2);
  unsigned short* WgT    = (unsigned short*)alloc((size_t)D * 2 * D * 2);
  unsigned short* memb   = (unsigned short*)alloc((size_t)NS * D * 2);
  float*          bkv    = (float*)alloc((size_t)2 * D * 4);
  float*          KV     = (float*)alloc((size_t)NS * 2 * D * 4);
  unsigned short* Kn     = (unsigned short*)alloc((size_t)NS * D * 2);
  unsigned short* Vt     = (unsigned short*)alloc((size_t)D * NS * 2);
  unsigned short* gatein = (unsigned short*)alloc((size_t)T * 2 * D * 2);  // [T,2048]: X | R
  unsigned short* Qb     = (unsigned short*)alloc((size_t)T * D * 2);      // Q bf16 (unnormalized)
  unsigned short* Wsm    = (unsigned short*)alloc((size_t)T * NS * 2);     // softmax weights bf16
  float*          S      = (float*)alloc((size_t)T * NS * 4);              // scores fp32
  float*          norm2  = (float*)alloc((size_t)T * 4);                   // ||Q_row||^2

  hipMemsetAsync(norm2, 0, (size_t)T * 4, stream);

  // --- prep: weight transposes to [N,K] bf16, converts ---
  k_transpose_bf16<<<dim3(32, 32), dim3(32, 8), 0, stream>>>(Wq, WqT, D, D);
  k_transpose_bf16<<<dim3(32, 32), dim3(32, 8), 0, stream>>>(Wk, WkvT, D, D);
  k_transpose_bf16<<<dim3(32, 32), dim3(32, 8), 0, stream>>>(Wv, WkvT + (size_t)D * D, D, D);
  k_transpose_bf16<<<dim3(32, 64), dim3(32, 8), 0, stream>>>(Wg, WgT, 2 * D, D);
  k_convert_bf16<<<512, 256, 0, stream>>>((const float4*)mem, (ushort4*)memb, NS * D / 4);
  k_concat_bias<<<8, 256, 0, stream>>>(bk, bv, bkv);
  k_stage_x<<<T * D / 4 / 256, 256, 0, stream>>>((const float4*)X, gatein, T * D / 4);

  // --- K,V: [512,2048] = memb @ [Wk|Wv] + [bk|bv] (tiny: old 128^2 kernel) ---
  k_gemm<0><<<dim3(2 * D / 128, NS / 128), 256, 0, stream>>>(
      memb, D, WkvT, D, bkv, 1.0f, KV, 2 * D, nullptr, 0, nullptr, D);
  k_post_kv<<<NS, 256, 0, stream>>>((const float4*)KV, Kn, Vt);

  // --- Q = X @ Wq + bq -> bf16 Qb + row norms (normalization deferred to softmax) ---
  k_gemm256<1><<<dim3(D / 256, T / 256), 512, 0, stream>>>(
      gatein, 2 * D, WqT, D, bq, 1.0f, nullptr, 0, Qb, D, norm2, D);

  // --- scores_raw = Q @ Kn^T (temperature applied in softmax) ---
  k_gemm256<0><<<dim3(NS / 256, T / 256), 512, 0, stream>>>(
      Qb, D, Kn, D, nullptr, 1.0f, S, NS, nullptr, 0, nullptr, D);
  k_softmax<<<T / 4, 256, 0, stream>>>((const float4*)S, norm2, Wsm);

  // --- R = w @ V -> bf16 into gate_in cols 1024.. ---
  k_gemm256<2><<<dim3(D / 256, T / 256), 512, 0, stream>>>(
      Wsm, NS, Vt, NS, nullptr, 1.0f, nullptr, 0, gatein + D, 2 * D, nullptr, NS);

  // --- gate: g = sigmoid([X,R] @ Wg + bg); out = g*x + (1-g)*r ---
  k_gemm256<3><<<dim3(D / 256, T / 256), 512, 0, stream>>>(
      gatein, 2 * D, WgT, 2 * D, bg, 1.0f, out, D, gatein, 2 * D, nullptr, 2 * D);

  (void)in_sizes; (void)n_in; (void)out_size; (void)ws_size;
}

// Round 4
// 610.765 us; speedup vs baseline: 1.0925x; 1.0855x over previous
//
#include <hip/hip_runtime.h>
#include <cstdint>

typedef __attribute__((ext_vector_type(8))) __bf16 bf16x8;
typedef __attribute__((ext_vector_type(4))) float f32x4;

__device__ __forceinline__ unsigned short f2bf(float f) {
  unsigned u = __float_as_uint(f);
  unsigned r = (u + 0x7FFFu + ((u >> 16) & 1u)) >> 16;  // RNE
  return (unsigned short)r;
}
__device__ __forceinline__ float bf2f(unsigned short u) {
  return __uint_as_float(((unsigned)u) << 16);
}

__device__ __forceinline__ __attribute__((address_space(3))) void* to_lds(void* p) {
  return (__attribute__((address_space(3))) void*)p;
}
__device__ __forceinline__ const __attribute__((address_space(1))) void* to_glb(const void* p) {
  return (const __attribute__((address_space(1))) void*)p;
}

// Inline-asm LDS read: keeps the DMA->ds_read dependence OUT of the compiler's
// waitcnt legalizer (it would otherwise insert vmcnt(0) before each phase's
// fragment reads, draining the prefetch queue). Ordering is carried by our
// barriers + lgkmcnt(0) + sched_barrier(0) + counted vmcnt.
template <int OFS>
__device__ __forceinline__ bf16x8 lds_rd(unsigned a) {
  bf16x8 r;
  asm volatile("ds_read_b128 %0, %1 offset:%2" : "=v"(r) : "v"(a), "i"(OFS));
  return r;
}

// ---------------- transpose: fp32 in[R,C] -> bf16 out[C,R] ----------------
__global__ void k_transpose_bf16(const float* __restrict__ in, unsigned short* __restrict__ out,
                                 int R, int C) {
  __shared__ float tile[32][33];
  int c0 = blockIdx.x * 32, r0 = blockIdx.y * 32;
  int tx = threadIdx.x, ty = threadIdx.y;  // block (32,8)
  #pragma unroll
  for (int i = 0; i < 32; i += 8)
    tile[ty + i][tx] = in[(size_t)(r0 + ty + i) * C + c0 + tx];
  __syncthreads();
  #pragma unroll
  for (int i = 0; i < 32; i += 8)
    out[(size_t)(c0 + ty + i) * R + r0 + tx] = f2bf(tile[tx][ty + i]);
}

// ---------------- fp32 -> bf16 contiguous ----------------
__global__ void k_convert_bf16(const float4* __restrict__ in, ushort4* __restrict__ out, int n4) {
  int i = blockIdx.x * blockDim.x + threadIdx.x;
  if (i < n4) {
    float4 v = in[i];
    ushort4 o; o.x = f2bf(v.x); o.y = f2bf(v.y); o.z = f2bf(v.z); o.w = f2bf(v.w);
    out[i] = o;
  }
}

// ---------------- X fp32 [T,1024] -> bf16 into gate_in[T,2048] cols 0..1023 ----------------
__global__ void k_stage_x(const float4* __restrict__ X, unsigned short* __restrict__ gate_in, int n4) {
  int i = blockIdx.x * blockDim.x + threadIdx.x;
  if (i < n4) {
    int flat = i << 2;
    int row = flat >> 10, col = flat & 1023;
    float4 v = X[i];
    ushort4 o; o.x = f2bf(v.x); o.y = f2bf(v.y); o.z = f2bf(v.z); o.w = f2bf(v.w);
    *(ushort4*)(gate_in + (size_t)row * 2048 + col) = o;
  }
}

__global__ void k_concat_bias(const float* __restrict__ bk, const float* __restrict__ bv,
                              float* __restrict__ bkv) {
  int i = blockIdx.x * blockDim.x + threadIdx.x;
  if (i < 2048) bkv[i] = (i < 1024) ? bk[i] : bv[i - 1024];
}

// ---------------- KV fp32 [512,2048] -> Kn bf16 [512,1024] (normalized), Vt bf16 [1024,512] ----------------
__global__ void k_post_kv(const float4* __restrict__ KV, unsigned short* __restrict__ Kn,
                          unsigned short* __restrict__ Vt) {
  int row = blockIdx.x;   // 512
  int tid = threadIdx.x;  // 256
  const float4* r = KV + (size_t)row * 512;
  float4 k4 = r[tid];
  float4 v4 = r[256 + tid];
  float s = k4.x * k4.x + k4.y * k4.y + k4.z * k4.z + k4.w * k4.w;
  #pragma unroll
  for (int m = 32; m; m >>= 1) s += __shfl_xor(s, m, 64);
  __shared__ float red[4];
  if ((tid & 63) == 0) red[tid >> 6] = s;
  __syncthreads();
  float tot = red[0] + red[1] + red[2] + red[3];
  float inv = 1.0f / fmaxf(sqrtf(tot), 1e-12f);
  ushort4 o; o.x = f2bf(k4.x * inv); o.y = f2bf(k4.y * inv);
  o.z = f2bf(k4.z * inv); o.w = f2bf(k4.w * inv);
  *(ushort4*)(Kn + (size_t)row * 1024 + tid * 4) = o;
  int vc = tid * 4;
  Vt[(size_t)(vc + 0) * 512 + row] = f2bf(v4.x);
  Vt[(size_t)(vc + 1) * 512 + row] = f2bf(v4.y);
  Vt[(size_t)(vc + 2) * 512 + row] = f2bf(v4.z);
  Vt[(size_t)(vc + 3) * 512 + row] = f2bf(v4.w);
}

// ---------------- softmax with per-row temperature: w = softmax(S * alpha_row) ----------------
__global__ void k_softmax(const float4* __restrict__ S, const float* __restrict__ norm2,
                          unsigned short* __restrict__ W) {
  int tid = threadIdx.x;
  int wv = tid >> 6, lane = tid & 63;
  int row = blockIdx.x * 4 + wv;
  float alpha = 0.03125f * rsqrtf(fmaxf(norm2[row], 1e-24f));
  const float4* sr = S + (size_t)row * 128;
  float4 a = sr[lane], b = sr[64 + lane];
  a.x *= alpha; a.y *= alpha; a.z *= alpha; a.w *= alpha;
  b.x *= alpha; b.y *= alpha; b.z *= alpha; b.w *= alpha;
  float m = fmaxf(fmaxf(fmaxf(a.x, a.y), fmaxf(a.z, a.w)),
                  fmaxf(fmaxf(b.x, b.y), fmaxf(b.z, b.w)));
  #pragma unroll
  for (int o = 32; o; o >>= 1) m = fmaxf(m, __shfl_xor(m, o, 64));
  a.x = __expf(a.x - m); a.y = __expf(a.y - m); a.z = __expf(a.z - m); a.w = __expf(a.w - m);
  b.x = __expf(b.x - m); b.y = __expf(b.y - m); b.z = __expf(b.z - m); b.w = __expf(b.w - m);
  float s = a.x + a.y + a.z + a.w + b.x + b.y + b.z + b.w;
  #pragma unroll
  for (int o = 32; o; o >>= 1) s += __shfl_xor(s, o, 64);
  float inv = 1.0f / s;
  ushort4 oa, ob;
  oa.x = f2bf(a.x * inv); oa.y = f2bf(a.y * inv); oa.z = f2bf(a.z * inv); oa.w = f2bf(a.w * inv);
  ob.x = f2bf(b.x * inv); ob.y = f2bf(b.y * inv); ob.z = f2bf(b.z * inv); ob.w = f2bf(b.w * inv);
  ushort4* wr = (ushort4*)(W + (size_t)row * 512);
  wr[lane] = oa; wr[64 + lane] = ob;
}

// ---------------- old 128x128 GEMM (kept for the tiny KV GEMM only) ----------------
template <int MODE>
__global__ __launch_bounds__(256, 2) void k_gemm(
    const unsigned short* __restrict__ A, int lda,
    const unsigned short* __restrict__ B, int ldb,
    const float* __restrict__ bias, float scale,
    float* __restrict__ C, int ldc,
    unsigned short* __restrict__ Cb, int ldcb,
    float* __restrict__ Cnorm,
    int K) {
  __shared__ __align__(16) unsigned short As[128 * 64];
  __shared__ __align__(16) unsigned short Bs[128 * 64];
  const int tid = threadIdx.x;
  const int lane = tid & 63, w = tid >> 6;

  int mt = blockIdx.y, nt = blockIdx.x;
  const int m0 = mt * 128, n0 = nt * 128;

  const int srow = lane >> 3;
  const int schunk = (lane & 7) ^ srow;
  const unsigned short* gA = A + (size_t)(m0 + w * 8 + srow) * lda + schunk * 8;
  const unsigned short* gB = B + (size_t)(n0 + w * 8 + srow) * ldb + schunk * 8;
  unsigned short* lA = As + (w * 8) * 64;
  unsigned short* lB = Bs + (w * 8) * 64;

  f32x4 acc[4][4];
  f32x4 zero = {0.f, 0.f, 0.f, 0.f};
  #pragma unroll
  for (int i = 0; i < 4; ++i)
    #pragma unroll
    for (int j = 0; j < 4; ++j) acc[i][j] = zero;

  const int fr = lane & 15, q = lane >> 4;
  const int wr = (w >> 1) * 64, wc = (w & 1) * 64;

  for (int k0 = 0; k0 < K; k0 += 64) {
    #pragma unroll
    for (int i = 0; i < 4; ++i) {
      __builtin_amdgcn_global_load_lds(to_glb(gA + (size_t)i * 32 * lda + k0),
                                       to_lds(lA + i * 32 * 64), 16, 0, 0);
      __builtin_amdgcn_global_load_lds(to_glb(gB + (size_t)i * 32 * ldb + k0),
                                       to_lds(lB + i * 32 * 64), 16, 0, 0);
    }
    __syncthreads();
    #pragma unroll
    for (int ks = 0; ks < 2; ++ks) {
      bf16x8 af[4], bfr[4];
      const int p = (ks * 4 + q) ^ (lane & 7);
      #pragma unroll
      for (int mi = 0; mi < 4; ++mi) {
        af[mi] = *(const bf16x8*)(As + (wr + mi * 16 + fr) * 64 + p * 8);
        bfr[mi] = *(const bf16x8*)(Bs + (wc + mi * 16 + fr) * 64 + p * 8);
      }
      #pragma unroll
      for (int mi = 0; mi < 4; ++mi)
        #pragma unroll
        for (int ni = 0; ni < 4; ++ni)
          acc[mi][ni] = __builtin_amdgcn_mfma_f32_16x16x32_bf16(af[mi], bfr[ni], acc[mi][ni], 0, 0, 0);
    }
    __syncthreads();
  }

  #pragma unroll
  for (int ni = 0; ni < 4; ++ni) {
    const int gc = n0 + wc + ni * 16 + fr;
    const float bv = bias ? bias[gc] : 0.0f;
    #pragma unroll
    for (int mi = 0; mi < 4; ++mi) {
      #pragma unroll
      for (int r = 0; r < 4; ++r) {
        const int gr = m0 + wr + mi * 16 + q * 4 + r;
        float c = acc[mi][ni][r] * scale + bv;
        C[(size_t)gr * ldc + gc] = c;
      }
    }
  }
  (void)Cb; (void)ldcb; (void)Cnorm;
}

// ---------------- 256x256 8-phase GEMM (T2+T3+T4+T5), C[M,N] = A[M,K] * B^T ([N,K]) ----------------
// 8 waves (2M x 4N), BK=64, per-wave C = 128x64 as interleaved quadrants:
//   rows: qm*128 + wm*64 + mi*16, cols: qn*128 + wn*32 + ni*16.
// LDS 128 KiB: As[2][256][64] + Bs[2][256][64] bf16, chunk-XOR swizzle
// (row r, logical k-chunk c stored at chunk c^(r&7)); staged via global_load_lds
// width-16 with pre-swizzled global source (linear LDS dest).
// Fragment reads are INLINE-ASM ds_read_b128 (base VGPR + offset: immediate for
// {buffer, quadrant, mi/ni}) so the compiler's LDS-DMA waitcnt legalizer cannot
// insert vmcnt(0) drains before them. vmcnt is counted manually: vmcnt(6) at
// ph4/ph8 only (3 half-tiles = 6 loads in flight), never 0 in the main loop.
template <int MODE>
__global__ __launch_bounds__(512, 2) void k_gemm256(
    const unsigned short* __restrict__ A, int lda,
    const unsigned short* __restrict__ B, int ldb,
    const float* __restrict__ bias, float scale,
    float* __restrict__ C, int ldc,
    unsigned short* __restrict__ Cb, int ldcb,
    float* __restrict__ Cnorm,
    int K) {
  __shared__ __align__(16) unsigned short As[2 * 256 * 64];
  __shared__ __align__(16) unsigned short Bs[2 * 256 * 64];
  const int tid = threadIdx.x;
  const int lane = tid & 63, w = tid >> 6;
  const int wm = w >> 2, wn = w & 3;
  const int fr = lane & 15, q = lane >> 4;

  // XCD-aware tile remap (gridDim.y % 8 == 0 for all call sites)
  int mt, nt;
  {
    int f = blockIdx.y * gridDim.x + blockIdx.x;
    int NTg = gridDim.x, MTg = gridDim.y;
    if ((MTg & 7) == 0) {
      int xcd = f & 7;
      int j = f >> 3;
      nt = j % NTg;
      mt = (j / NTg) * 8 + xcd;
    } else {
      mt = blockIdx.y; nt = blockIdx.x;
    }
  }
  const int m0 = mt * 256, n0 = nt * 256;

  const int lr = lane >> 3;              // row within the wave's 8-row group
  const int lc = ((lane & 7) ^ lr) * 8;  // pre-swizzled source k-offset (elems)
  const int NT_ = K >> 6;                // number of 64-wide K-tiles
  const int NITER = NT_ >> 1;

  unsigned short* As0 = As;
  unsigned short* As1 = As + 256 * 64;
  unsigned short* Bs0 = Bs;
  unsigned short* Bs1 = Bs + 256 * 64;

  // LDS byte-address bases for the asm fragment reads (32-bit LDS offsets).
  const unsigned AsB = (unsigned)(size_t)to_lds(As);
  const unsigned BsB = (unsigned)(size_t)to_lds(Bs);
  const unsigned ch0 = (unsigned)((q ^ (fr & 7)) * 16);
  const unsigned vA0 = AsB + (unsigned)((wm * 64 + fr) * 128) + ch0;
  const unsigned vA1 = AsB + (unsigned)((wm * 64 + fr) * 128) + (ch0 ^ 64u);
  const unsigned vB0 = BsB + (unsigned)((wn * 32 + fr) * 128) + ch0;
  const unsigned vB1 = BsB + (unsigned)((wn * 32 + fr) * 128) + (ch0 ^ 64u);

  f32x4 acc[2][2][4][2];
  {
    f32x4 zero = {0.f, 0.f, 0.f, 0.f};
    #pragma unroll
    for (int a = 0; a < 2; ++a)
      #pragma unroll
      for (int b = 0; b < 2; ++b)
        #pragma unroll
        for (int c = 0; c < 4; ++c)
          #pragma unroll
          for (int d = 0; d < 2; ++d) acc[a][b][c][d] = zero;
  }

// stage one half-tile (128 rows x 64 cols): 2 x global_load_lds(16B) per thread
#define STG(g, ld, rbase, h, kt, L) do {                                        \
    int k0s = ((kt) < NT_ ? (kt) : (NT_ - 1)) * 64;                             \
    _Pragma("unroll")                                                           \
    for (int j = 0; j < 2; ++j) {                                               \
      __builtin_amdgcn_global_load_lds(                                         \
          to_glb((g) + (size_t)((rbase) + (h) * 128 + j * 64 + w * 8 + lr) *    \
                           (size_t)(ld) + k0s + lc),                            \
          to_lds((L) + ((h) * 128 + j * 64 + w * 8) * 64), 16, 0, 0);           \
    } } while (0)

// BUF,QM,mi folded into the ds_read offset immediate: BUF*32768 + QM*16384 + mi*2048
#define RD_A(BUF, QM) do {                                                      \
    a_f[0][0] = lds_rd<(BUF) * 32768 + (QM) * 16384 + 0 * 2048>(vA0);           \
    a_f[0][1] = lds_rd<(BUF) * 32768 + (QM) * 16384 + 1 * 2048>(vA0);           \
    a_f[0][2] = lds_rd<(BUF) * 32768 + (QM) * 16384 + 2 * 2048>(vA0);           \
    a_f[0][3] = lds_rd<(BUF) * 32768 + (QM) * 16384 + 3 * 2048>(vA0);           \
    a_f[1][0] = lds_rd<(BUF) * 32768 + (QM) * 16384 + 0 * 2048>(vA1);           \
    a_f[1][1] = lds_rd<(BUF) * 32768 + (QM) * 16384 + 1 * 2048>(vA1);           \
    a_f[1][2] = lds_rd<(BUF) * 32768 + (QM) * 16384 + 2 * 2048>(vA1);           \
    a_f[1][3] = lds_rd<(BUF) * 32768 + (QM) * 16384 + 3 * 2048>(vA1);           \
  } while (0)

#define RD_B(BUF, QN, dst) do {                                                 \
    dst[0][0] = lds_rd<(BUF) * 32768 + (QN) * 16384 + 0 * 2048>(vB0);           \
    dst[0][1] = lds_rd<(BUF) * 32768 + (QN) * 16384 + 1 * 2048>(vB0);           \
    dst[1][0] = lds_rd<(BUF) * 32768 + (QN) * 16384 + 0 * 2048>(vB1);           \
    dst[1][1] = lds_rd<(BUF) * 32768 + (QN) * 16384 + 1 * 2048>(vB1);           \
  } while (0)

#define MQ(QM, QN, bsrc) do {                                                   \
    _Pragma("unroll")                                                           \
    for (int ks = 0; ks < 2; ++ks)                                              \
      _Pragma("unroll")                                                         \
      for (int mi = 0; mi < 4; ++mi)                                            \
        _Pragma("unroll")                                                       \
        for (int ni = 0; ni < 2; ++ni)                                          \
          acc[QM][QN][mi][ni] = __builtin_amdgcn_mfma_f32_16x16x32_bf16(        \
              a_f[ks][mi], bsrc[ks][ni], acc[QM][QN][mi][ni], 0, 0, 0);         \
  } while (0)

#define BAR_MID() do {                                                          \
    __builtin_amdgcn_s_barrier();                                               \
    asm volatile("s_waitcnt lgkmcnt(0)" ::: "memory");                          \
    __builtin_amdgcn_sched_barrier(0);                                          \
    __builtin_amdgcn_s_setprio(1);                                              \
  } while (0)

// phase end without vmem wait (T4: loads stay in flight across barriers)
#define BAR_END() do {                                                          \
    __builtin_amdgcn_s_setprio(0);                                              \
    __builtin_amdgcn_s_barrier();                                               \
  } while (0)

// phase end WITH counted vmem wait (only ph4 / ph8)
#define BAR_END_VM() do {                                                       \
    __builtin_amdgcn_s_setprio(0);                                              \
    asm volatile("s_waitcnt vmcnt(6)" ::: "memory");                            \
    __builtin_amdgcn_s_barrier();                                               \
  } while (0)

  // prologue: 7 half-tiles (tile0 full into buf0; tile1 Ah0,Bh0,Bh1 into buf1);
  // vmcnt(6) pins stages 1..4 (= all of buf0) before the ph1..ph3 reads.
  STG(A, lda, m0, 0, 0, As0);  // s1 buf0.Ah0
  STG(B, ldb, n0, 0, 0, Bs0);  // s2 buf0.Bh0
  STG(B, ldb, n0, 1, 0, Bs0);  // s3 buf0.Bh1
  STG(A, lda, m0, 1, 0, As0);  // s4 buf0.Ah1
  STG(A, lda, m0, 0, 1, As1);  // s5 buf1.Ah0
  STG(B, ldb, n0, 0, 1, Bs1);  // s6 buf1.Bh0
  STG(B, ldb, n0, 1, 1, Bs1);  // s7 buf1.Bh1
  asm volatile("s_waitcnt vmcnt(6)" ::: "memory");
  __builtin_amdgcn_s_barrier();

  bf16x8 a_f[2][4], b0[2][2], b1[2][2];

  for (int it = 0; it < NITER; ++it) {
    const int t = it * 2;
    // ph1
    RD_A(0, 0); RD_B(0, 0, b0);
    STG(A, lda, m0, 1, t + 1, As1);      // buf1.Ah1 <- t+1 (read ph7)
    BAR_MID(); MQ(0, 0, b0); BAR_END();
    // ph2
    RD_B(0, 1, b1);
    STG(A, lda, m0, 0, t + 2, As0);      // buf0.Ah0 <- t+2
    BAR_MID(); MQ(0, 1, b1); BAR_END();
    // ph3
    RD_A(0, 1);
    STG(B, ldb, n0, 0, t + 2, Bs0);      // buf0.Bh0 <- t+2
    BAR_MID(); MQ(1, 0, b0); BAR_END();
    // ph4
    STG(B, ldb, n0, 1, t + 2, Bs0);      // buf0.Bh1 <- t+2
    BAR_MID(); MQ(1, 1, b1); BAR_END_VM();
    // ph5
    RD_A(1, 0); RD_B(1, 0, b0);
    STG(A, lda, m0, 1, t + 2, As0);      // buf0.Ah1 <- t+2
    BAR_MID(); MQ(0, 0, b0); BAR_END();
    // ph6
    RD_B(1, 1, b1);
    STG(A, lda, m0, 0, t + 3, As1);      // buf1.Ah0 <- t+3
    BAR_MID(); MQ(0, 1, b1); BAR_END();
    // ph7
    RD_A(1, 1);
    STG(B, ldb, n0, 0, t + 3, Bs1);      // buf1.Bh0 <- t+3
    BAR_MID(); MQ(1, 0, b0); BAR_END();
    // ph8
    STG(B, ldb, n0, 1, t + 3, Bs1);      // buf1.Bh1 <- t+3
    BAR_MID(); MQ(1, 1, b1); BAR_END_VM();
  }

  // drain pending LDS-DMA (only the clamped redundant tail stages remain)
  asm volatile("s_waitcnt vmcnt(0)" ::: "memory");
  __builtin_amdgcn_sched_barrier(0);

#undef STG
#undef RD_A
#undef RD_B
#undef MQ
#undef BAR_MID
#undef BAR_END
#undef BAR_END_VM

  if (MODE == 1) {
    // bf16 store + per-row sum-of-squares accumulation (deferred l2-norm)
    #pragma unroll
    for (int qm = 0; qm < 2; ++qm)
      #pragma unroll
      for (int mi = 0; mi < 4; ++mi) {
        float s2[4] = {0.f, 0.f, 0.f, 0.f};
        #pragma unroll
        for (int qn = 0; qn < 2; ++qn)
          #pragma unroll
          for (int ni = 0; ni < 2; ++ni) {
            const int gc = n0 + qn * 128 + wn * 32 + ni * 16 + fr;
            const float bv = bias[gc];
            #pragma unroll
            for (int r = 0; r < 4; ++r) {
              const int gr = m0 + qm * 128 + wm * 64 + mi * 16 + q * 4 + r;
              float c = acc[qm][qn][mi][ni][r] + bv;
              Cb[(size_t)gr * ldcb + gc] = f2bf(c);
              s2[r] += c * c;
            }
          }
        #pragma unroll
        for (int r = 0; r < 4; ++r) {
          float v = s2[r];
          v += __shfl_xor(v, 1, 64);
          v += __shfl_xor(v, 2, 64);
          v += __shfl_xor(v, 4, 64);
          v += __shfl_xor(v, 8, 64);
          if (fr == 0)
            atomicAdd(Cnorm + (m0 + qm * 128 + wm * 64 + mi * 16 + q * 4 + r), v);
        }
      }
  } else {
    #pragma unroll
    for (int qm = 0; qm < 2; ++qm)
      #pragma unroll
      for (int qn = 0; qn < 2; ++qn)
        #pragma unroll
        for (int ni = 0; ni < 2; ++ni) {
          const int gc = n0 + qn * 128 + wn * 32 + ni * 16 + fr;
          const float bv = bias ? bias[gc] : 0.0f;
          #pragma unroll
          for (int mi = 0; mi < 4; ++mi)
            #pragma unroll
            for (int r = 0; r < 4; ++r) {
              const int gr = m0 + qm * 128 + wm * 64 + mi * 16 + q * 4 + r;
              float c = acc[qm][qn][mi][ni][r] * scale + bv;
              if (MODE == 0) {
                C[(size_t)gr * ldc + gc] = c;
              } else if (MODE == 2) {
                Cb[(size_t)gr * ldcb + gc] = f2bf(c);
              } else {  // MODE 3: fused sigmoid gate
                float g = 1.0f / (1.0f + __expf(-c));
                float x = bf2f(Cb[(size_t)gr * ldcb + gc]);
                float rr = bf2f(Cb[(size_t)gr * ldcb + 1024 + gc]);
                C[(size_t)gr * ldc + gc] = g * x + (1.0f - g) * rr;
              }
            }
        }
  }
}

extern "C" void kernel_launch(void* const* d_in, const int* in_sizes, int n_in,
                              void* d_out, int out_size, void* d_ws, size_t ws_size,
                              hipStream_t stream) {
  const float* X   = (const float*)d_in[0];
  const float* mem = (const float*)d_in[1];
  const float* Wq  = (const float*)d_in[2];
  const float* bq  = (const float*)d_in[3];
  const float* Wk  = (const float*)d_in[4];
  const float* bk  = (const float*)d_in[5];
  const float* Wv  = (const float*)d_in[6];
  const float* bv  = (const float*)d_in[7];
  const float* Wg  = (const float*)d_in[8];
  const float* bg  = (const float*)d_in[9];
  float* out = (float*)d_out;

  const int T = 32768, D = 1024, NS = 512;

  char* p = (char*)d_ws;
  auto alloc = [&](size_t b) { char* r = p; p += (b + 255) & ~(size_t)255; return r; };
  unsigned short* WqT    = (unsigned short*)alloc((size_t)D * D * 2);
  unsigned short* WkvT   = (unsigned short*)alloc((size_t)2 * D * D * 2);
  unsigned short* WgT    = (unsigned short*)alloc((size_t)D * 2 * D * 2);
  unsigned short* memb   = (unsigned short*)alloc((size_t)NS * D * 2);
  float*          bkv    = (float*)alloc((size_t)2 * D * 4);
  float*          KV     = (float*)alloc((size_t)NS * 2 * D * 4);
  unsigned short* Kn     = (unsigned short*)alloc((size_t)NS * D * 2);
  unsigned short* Vt     = (unsigned short*)alloc((size_t)D * NS * 2);
  unsigned short* gatein = (unsigned short*)alloc((size_t)T * 2 * D * 2);  // [T,2048]: X | R
  unsigned short* Qb     = (unsigned short*)alloc((size_t)T * D * 2);      // Q bf16 (unnormalized)
  unsigned short* Wsm    = (unsigned short*)alloc((size_t)T * NS * 2);     // softmax weights bf16
  float*          S      = (float*)alloc((size_t)T * NS * 4);              // scores fp32
  float*          norm2  = (float*)alloc((size_t)T * 4);                   // ||Q_row||^2

  hipMemsetAsync(norm2, 0, (size_t)T * 4, stream);

  // --- prep: weight transposes to [N,K] bf16, converts ---
  k_transpose_bf16<<<dim3(32, 32), dim3(32, 8), 0, stream>>>(Wq, WqT, D, D);
  k_transpose_bf16<<<dim3(32, 32), dim3(32, 8), 0, stream>>>(Wk, WkvT, D, D);
  k_transpose_bf16<<<dim3(32, 32), dim3(32, 8), 0, stream>>>(Wv, WkvT + (size_t)D * D, D, D);
  k_transpose_bf16<<<dim3(32, 64), dim3(32, 8), 0, stream>>>(Wg, WgT, 2 * D, D);
  k_convert_bf16<<<512, 256, 0, stream>>>((const float4*)mem, (ushort4*)memb, NS * D / 4);
  k_concat_bias<<<8, 256, 0, stream>>>(bk, bv, bkv);
  k_stage_x<<<T * D / 4 / 256, 256, 0, stream>>>((const float4*)X, gatein, T * D / 4);

  // --- K,V: [512,2048] = memb @ [Wk|Wv] + [bk|bv] (tiny: old 128^2 kernel) ---
  k_gemm<0><<<dim3(2 * D / 128, NS / 128), 256, 0, stream>>>(
      memb, D, WkvT, D, bkv, 1.0f, KV, 2 * D, nullptr, 0, nullptr, D);
  k_post_kv<<<NS, 256, 0, stream>>>((const float4*)KV, Kn, Vt);

  // --- Q = X @ Wq + bq -> bf16 Qb + row norms (normalization deferred to softmax) ---
  k_gemm256<1><<<dim3(D / 256, T / 256), 512, 0, stream>>>(
      gatein, 2 * D, WqT, D, bq, 1.0f, nullptr, 0, Qb, D, norm2, D);

  // --- scores_raw = Q @ Kn^T (temperature applied in softmax) ---
  k_gemm256<0><<<dim3(NS / 256, T / 256), 512, 0, stream>>>(
      Qb, D, Kn, D, nullptr, 1.0f, S, NS, nullptr, 0, nullptr, D);
  k_softmax<<<T / 4, 256, 0, stream>>>((const float4*)S, norm2, Wsm);

  // --- R = w @ V -> bf16 into gate_in cols 1024.. ---
  k_gemm256<2><<<dim3(D / 256, T / 256), 512, 0, stream>>>(
      Wsm, NS, Vt, NS, nullptr, 1.0f, nullptr, 0, gatein + D, 2 * D, nullptr, NS);

  // --- gate: g = sigmoid([X,R] @ Wg + bg); out = g*x + (1-g)*r ---
  k_gemm256<3><<<dim3(D / 256, T / 256), 512, 0, stream>>>(
      gatein, 2 * D, WgT, 2 * D, bg, 1.0f, out, D, gatein, 2 * D, nullptr, 2 * D);

  (void)in_sizes; (void)n_in; (void)out_size; (void)ws_size;
}

// Round 5
// 597.582 us; speedup vs baseline: 1.1166x; 1.0221x over previous
//
#include <hip/hip_runtime.h>
#include <cstdint>

typedef __attribute__((ext_vector_type(8))) __bf16 bf16x8;
typedef __attribute__((ext_vector_type(4))) float f32x4;

__device__ __forceinline__ unsigned short f2bf(float f) {
  unsigned u = __float_as_uint(f);
  unsigned r = (u + 0x7FFFu + ((u >> 16) & 1u)) >> 16;  // RNE
  return (unsigned short)r;
}
__device__ __forceinline__ float bf2f(unsigned short u) {
  return __uint_as_float(((unsigned)u) << 16);
}

__device__ __forceinline__ __attribute__((address_space(3))) void* to_lds(void* p) {
  return (__attribute__((address_space(3))) void*)p;
}
__device__ __forceinline__ const __attribute__((address_space(1))) void* to_glb(const void* p) {
  return (const __attribute__((address_space(1))) void*)p;
}

// Inline-asm LDS read: keeps the DMA->ds_read dependence OUT of the compiler's
// waitcnt legalizer. Ordering is carried by barriers + counted waitcnts.
template <int OFS>
__device__ __forceinline__ bf16x8 lds_rd(unsigned a) {
  bf16x8 r;
  asm volatile("ds_read_b128 %0, %1 offset:%2" : "=v"(r) : "v"(a), "i"(OFS));
  return r;
}

// ---------------- transpose: fp32 in[R,C] -> bf16 out[C,R] ----------------
__global__ void k_transpose_bf16(const float* __restrict__ in, unsigned short* __restrict__ out,
                                 int R, int C) {
  __shared__ float tile[32][33];
  int c0 = blockIdx.x * 32, r0 = blockIdx.y * 32;
  int tx = threadIdx.x, ty = threadIdx.y;  // block (32,8)
  #pragma unroll
  for (int i = 0; i < 32; i += 8)
    tile[ty + i][tx] = in[(size_t)(r0 + ty + i) * C + c0 + tx];
  __syncthreads();
  #pragma unroll
  for (int i = 0; i < 32; i += 8)
    out[(size_t)(c0 + ty + i) * R + r0 + tx] = f2bf(tile[tx][ty + i]);
}

// ---------------- fp32 -> bf16 contiguous ----------------
__global__ void k_convert_bf16(const float4* __restrict__ in, ushort4* __restrict__ out, int n4) {
  int i = blockIdx.x * blockDim.x + threadIdx.x;
  if (i < n4) {
    float4 v = in[i];
    ushort4 o; o.x = f2bf(v.x); o.y = f2bf(v.y); o.z = f2bf(v.z); o.w = f2bf(v.w);
    out[i] = o;
  }
}

// ---------------- X fp32 [T,1024] -> bf16 into gate_in[T,2048] cols 0..1023 ----------------
__global__ void k_stage_x(const float4* __restrict__ X, unsigned short* __restrict__ gate_in, int n4) {
  int i = blockIdx.x * blockDim.x + threadIdx.x;
  if (i < n4) {
    int flat = i << 2;
    int row = flat >> 10, col = flat & 1023;
    float4 v = X[i];
    ushort4 o; o.x = f2bf(v.x); o.y = f2bf(v.y); o.z = f2bf(v.z); o.w = f2bf(v.w);
    *(ushort4*)(gate_in + (size_t)row * 2048 + col) = o;
  }
}

__global__ void k_concat_bias(const float* __restrict__ bk, const float* __restrict__ bv,
                              float* __restrict__ bkv) {
  int i = blockIdx.x * blockDim.x + threadIdx.x;
  if (i < 2048) bkv[i] = (i < 1024) ? bk[i] : bv[i - 1024];
}

// ---------------- KV fp32 [512,2048] -> Kn bf16 [512,1024] (normalized), Vt bf16 [1024,512] ----------------
__global__ void k_post_kv(const float4* __restrict__ KV, unsigned short* __restrict__ Kn,
                          unsigned short* __restrict__ Vt) {
  int row = blockIdx.x;   // 512
  int tid = threadIdx.x;  // 256
  const float4* r = KV + (size_t)row * 512;
  float4 k4 = r[tid];
  float4 v4 = r[256 + tid];
  float s = k4.x * k4.x + k4.y * k4.y + k4.z * k4.z + k4.w * k4.w;
  #pragma unroll
  for (int m = 32; m; m >>= 1) s += __shfl_xor(s, m, 64);
  __shared__ float red[4];
  if ((tid & 63) == 0) red[tid >> 6] = s;
  __syncthreads();
  float tot = red[0] + red[1] + red[2] + red[3];
  float inv = 1.0f / fmaxf(sqrtf(tot), 1e-12f);
  ushort4 o; o.x = f2bf(k4.x * inv); o.y = f2bf(k4.y * inv);
  o.z = f2bf(k4.z * inv); o.w = f2bf(k4.w * inv);
  *(ushort4*)(Kn + (size_t)row * 1024 + tid * 4) = o;
  int vc = tid * 4;
  Vt[(size_t)(vc + 0) * 512 + row] = f2bf(v4.x);
  Vt[(size_t)(vc + 1) * 512 + row] = f2bf(v4.y);
  Vt[(size_t)(vc + 2) * 512 + row] = f2bf(v4.z);
  Vt[(size_t)(vc + 3) * 512 + row] = f2bf(v4.w);
}

// ---------------- softmax with per-row temperature: w = softmax(S * alpha_row) ----------------
__global__ void k_softmax(const float4* __restrict__ S, const float* __restrict__ norm2,
                          unsigned short* __restrict__ W) {
  int tid = threadIdx.x;
  int wv = tid >> 6, lane = tid & 63;
  int row = blockIdx.x * 4 + wv;
  float alpha = 0.03125f * rsqrtf(fmaxf(norm2[row], 1e-24f));
  const float4* sr = S + (size_t)row * 128;
  float4 a = sr[lane], b = sr[64 + lane];
  a.x *= alpha; a.y *= alpha; a.z *= alpha; a.w *= alpha;
  b.x *= alpha; b.y *= alpha; b.z *= alpha; b.w *= alpha;
  float m = fmaxf(fmaxf(fmaxf(a.x, a.y), fmaxf(a.z, a.w)),
                  fmaxf(fmaxf(b.x, b.y), fmaxf(b.z, b.w)));
  #pragma unroll
  for (int o = 32; o; o >>= 1) m = fmaxf(m, __shfl_xor(m, o, 64));
  a.x = __expf(a.x - m); a.y = __expf(a.y - m); a.z = __expf(a.z - m); a.w = __expf(a.w - m);
  b.x = __expf(b.x - m); b.y = __expf(b.y - m); b.z = __expf(b.z - m); b.w = __expf(b.w - m);
  float s = a.x + a.y + a.z + a.w + b.x + b.y + b.z + b.w;
  #pragma unroll
  for (int o = 32; o; o >>= 1) s += __shfl_xor(s, o, 64);
  float inv = 1.0f / s;
  ushort4 oa, ob;
  oa.x = f2bf(a.x * inv); oa.y = f2bf(a.y * inv); oa.z = f2bf(a.z * inv); oa.w = f2bf(a.w * inv);
  ob.x = f2bf(b.x * inv); ob.y = f2bf(b.y * inv); ob.z = f2bf(b.z * inv); ob.w = f2bf(b.w * inv);
  ushort4* wr = (ushort4*)(W + (size_t)row * 512);
  wr[lane] = oa; wr[64 + lane] = ob;
}

// ---------------- old 128x128 GEMM (kept for the tiny KV GEMM only) ----------------
template <int MODE>
__global__ __launch_bounds__(256, 2) void k_gemm(
    const unsigned short* __restrict__ A, int lda,
    const unsigned short* __restrict__ B, int ldb,
    const float* __restrict__ bias, float scale,
    float* __restrict__ C, int ldc,
    unsigned short* __restrict__ Cb, int ldcb,
    float* __restrict__ Cnorm,
    int K) {
  __shared__ __align__(16) unsigned short As[128 * 64];
  __shared__ __align__(16) unsigned short Bs[128 * 64];
  const int tid = threadIdx.x;
  const int lane = tid & 63, w = tid >> 6;

  int mt = blockIdx.y, nt = blockIdx.x;
  const int m0 = mt * 128, n0 = nt * 128;

  const int srow = lane >> 3;
  const int schunk = (lane & 7) ^ srow;
  const unsigned short* gA = A + (size_t)(m0 + w * 8 + srow) * lda + schunk * 8;
  const unsigned short* gB = B + (size_t)(n0 + w * 8 + srow) * ldb + schunk * 8;
  unsigned short* lA = As + (w * 8) * 64;
  unsigned short* lB = Bs + (w * 8) * 64;

  f32x4 acc[4][4];
  f32x4 zero = {0.f, 0.f, 0.f, 0.f};
  #pragma unroll
  for (int i = 0; i < 4; ++i)
    #pragma unroll
    for (int j = 0; j < 4; ++j) acc[i][j] = zero;

  const int fr = lane & 15, q = lane >> 4;
  const int wr = (w >> 1) * 64, wc = (w & 1) * 64;

  for (int k0 = 0; k0 < K; k0 += 64) {
    #pragma unroll
    for (int i = 0; i < 4; ++i) {
      __builtin_amdgcn_global_load_lds(to_glb(gA + (size_t)i * 32 * lda + k0),
                                       to_lds(lA + i * 32 * 64), 16, 0, 0);
      __builtin_amdgcn_global_load_lds(to_glb(gB + (size_t)i * 32 * ldb + k0),
                                       to_lds(lB + i * 32 * 64), 16, 0, 0);
    }
    __syncthreads();
    #pragma unroll
    for (int ks = 0; ks < 2; ++ks) {
      bf16x8 af[4], bfr[4];
      const int p = (ks * 4 + q) ^ (lane & 7);
      #pragma unroll
      for (int mi = 0; mi < 4; ++mi) {
        af[mi] = *(const bf16x8*)(As + (wr + mi * 16 + fr) * 64 + p * 8);
        bfr[mi] = *(const bf16x8*)(Bs + (wc + mi * 16 + fr) * 64 + p * 8);
      }
      #pragma unroll
      for (int mi = 0; mi < 4; ++mi)
        #pragma unroll
        for (int ni = 0; ni < 4; ++ni)
          acc[mi][ni] = __builtin_amdgcn_mfma_f32_16x16x32_bf16(af[mi], bfr[ni], acc[mi][ni], 0, 0, 0);
    }
    __syncthreads();
  }

  #pragma unroll
  for (int ni = 0; ni < 4; ++ni) {
    const int gc = n0 + wc + ni * 16 + fr;
    const float bv = bias ? bias[gc] : 0.0f;
    #pragma unroll
    for (int mi = 0; mi < 4; ++mi) {
      #pragma unroll
      for (int r = 0; r < 4; ++r) {
        const int gr = m0 + wr + mi * 16 + q * 4 + r;
        float c = acc[mi][ni][r] * scale + bv;
        C[(size_t)gr * ldc + gc] = c;
      }
    }
  }
  (void)Cb; (void)ldcb; (void)Cnorm;
}

// ---------------- 256x256 8-phase GEMM, read-ahead pipelined ----------------
// C[M,N] = A[M,K] * B^T ([N,K]). 8 waves (2M x 4N), BK=64, per-wave C = 128x64.
// LDS 128 KiB: As[2][256][64] + Bs[2][256][64] bf16, chunk-XOR swizzle, staged
// via global_load_lds w16 (pre-swizzled global source, linear LDS dest).
//
// SINGLE barrier per phase; each region r = [waitcnt -> reads/STG/MFMA -> barrier].
// Fragment reads are hoisted into the region where their target regs are dead:
//   R1 pre : b1<-Bs0.QN1      R2 post: a_f<-As0.QM1
//   R4 post: a_f<-As1.QM0, b0<-Bs1.QN0      R5 pre : b1<-Bs1.QN1
//   R6 post: a_f<-As1.QM1    R8 post: a_f<-As0.QM0, b0<-Bs0.QN0
// so every phase's lgkmcnt(0) waits only residue (LDS drain overlaps MFMA/barrier).
//
// Counted waits (per-wave vmcnt + barrier observation => cross-wave guarantee):
// uniform "s_waitcnt vmcnt(6) lgkmcnt(0)" at region start pins all stages with
// phase-distance >= 5 for EVERY wave by the time region r executes (a wave at r
// has observed all waves' (r-1)-start waits via the single barrier). All reads
// in the schedule sit at distance exactly >= 5 (verified per phase). STG targets
// are disjoint from all reads issued in the same or previous region (verified).
template <int MODE>
__global__ __launch_bounds__(512, 2) void k_gemm256(
    const unsigned short* __restrict__ A, int lda,
    const unsigned short* __restrict__ B, int ldb,
    const float* __restrict__ bias, float scale,
    float* __restrict__ C, int ldc,
    unsigned short* __restrict__ Cb, int ldcb,
    float* __restrict__ Cnorm,
    int K) {
  __shared__ __align__(16) unsigned short As[2 * 256 * 64];
  __shared__ __align__(16) unsigned short Bs[2 * 256 * 64];
  const int tid = threadIdx.x;
  const int lane = tid & 63, w = tid >> 6;
  const int wm = w >> 2, wn = w & 3;
  const int fr = lane & 15, q = lane >> 4;

  // XCD-aware tile remap (gridDim.y % 8 == 0 for all call sites)
  int mt, nt;
  {
    int f = blockIdx.y * gridDim.x + blockIdx.x;
    int NTg = gridDim.x, MTg = gridDim.y;
    if ((MTg & 7) == 0) {
      int xcd = f & 7;
      int j = f >> 3;
      nt = j % NTg;
      mt = (j / NTg) * 8 + xcd;
    } else {
      mt = blockIdx.y; nt = blockIdx.x;
    }
  }
  const int m0 = mt * 256, n0 = nt * 256;

  const int lr = lane >> 3;              // row within the wave's 8-row group
  const int lc = ((lane & 7) ^ lr) * 8;  // pre-swizzled source k-offset (elems)
  const int NT_ = K >> 6;                // number of 64-wide K-tiles
  const int NITER = NT_ >> 1;

  unsigned short* As0 = As;
  unsigned short* As1 = As + 256 * 64;
  unsigned short* Bs0 = Bs;
  unsigned short* Bs1 = Bs + 256 * 64;

  // LDS byte-address bases for the asm fragment reads (32-bit LDS offsets).
  const unsigned AsB = (unsigned)(size_t)to_lds(As);
  const unsigned BsB = (unsigned)(size_t)to_lds(Bs);
  const unsigned ch0 = (unsigned)((q ^ (fr & 7)) * 16);
  const unsigned vA0 = AsB + (unsigned)((wm * 64 + fr) * 128) + ch0;
  const unsigned vA1 = AsB + (unsigned)((wm * 64 + fr) * 128) + (ch0 ^ 64u);
  const unsigned vB0 = BsB + (unsigned)((wn * 32 + fr) * 128) + ch0;
  const unsigned vB1 = BsB + (unsigned)((wn * 32 + fr) * 128) + (ch0 ^ 64u);

  f32x4 acc[2][2][4][2];
  {
    f32x4 zero = {0.f, 0.f, 0.f, 0.f};
    #pragma unroll
    for (int a = 0; a < 2; ++a)
      #pragma unroll
      for (int b = 0; b < 2; ++b)
        #pragma unroll
        for (int c = 0; c < 4; ++c)
          #pragma unroll
          for (int d = 0; d < 2; ++d) acc[a][b][c][d] = zero;
  }

// stage one half-tile (128 rows x 64 cols): 2 x global_load_lds(16B) per thread
#define STG(g, ld, rbase, h, kt, L) do {                                        \
    int k0s = ((kt) < NT_ ? (kt) : (NT_ - 1)) * 64;                             \
    _Pragma("unroll")                                                           \
    for (int j = 0; j < 2; ++j) {                                               \
      __builtin_amdgcn_global_load_lds(                                         \
          to_glb((g) + (size_t)((rbase) + (h) * 128 + j * 64 + w * 8 + lr) *    \
                           (size_t)(ld) + k0s + lc),                            \
          to_lds((L) + ((h) * 128 + j * 64 + w * 8) * 64), 16, 0, 0);           \
    } } while (0)

// BUF,QM,mi folded into the ds_read offset immediate: BUF*32768 + QM*16384 + mi*2048
#define RD_A(BUF, QM) do {                                                      \
    a_f[0][0] = lds_rd<(BUF) * 32768 + (QM) * 16384 + 0 * 2048>(vA0);           \
    a_f[0][1] = lds_rd<(BUF) * 32768 + (QM) * 16384 + 1 * 2048>(vA0);           \
    a_f[0][2] = lds_rd<(BUF) * 32768 + (QM) * 16384 + 2 * 2048>(vA0);           \
    a_f[0][3] = lds_rd<(BUF) * 32768 + (QM) * 16384 + 3 * 2048>(vA0);           \
    a_f[1][0] = lds_rd<(BUF) * 32768 + (QM) * 16384 + 0 * 2048>(vA1);           \
    a_f[1][1] = lds_rd<(BUF) * 32768 + (QM) * 16384 + 1 * 2048>(vA1);           \
    a_f[1][2] = lds_rd<(BUF) * 32768 + (QM) * 16384 + 2 * 2048>(vA1);           \
    a_f[1][3] = lds_rd<(BUF) * 32768 + (QM) * 16384 + 3 * 2048>(vA1);           \
  } while (0)

#define RD_B(BUF, QN, dst) do {                                                 \
    dst[0][0] = lds_rd<(BUF) * 32768 + (QN) * 16384 + 0 * 2048>(vB0);           \
    dst[0][1] = lds_rd<(BUF) * 32768 + (QN) * 16384 + 1 * 2048>(vB0);           \
    dst[1][0] = lds_rd<(BUF) * 32768 + (QN) * 16384 + 0 * 2048>(vB1);           \
    dst[1][1] = lds_rd<(BUF) * 32768 + (QN) * 16384 + 1 * 2048>(vB1);           \
  } while (0)

#define MQ(QM, QN, bsrc) do {                                                   \
    _Pragma("unroll")                                                           \
    for (int ks = 0; ks < 2; ++ks)                                              \
      _Pragma("unroll")                                                         \
      for (int mi = 0; mi < 4; ++mi)                                            \
        _Pragma("unroll")                                                       \
        for (int ni = 0; ni < 2; ++ni)                                          \
          acc[QM][QN][mi][ni] = __builtin_amdgcn_mfma_f32_16x16x32_bf16(        \
              a_f[ks][mi], bsrc[ks][ni], acc[QM][QN][mi][ni], 0, 0, 0);         \
  } while (0)

// region start: frags for this region's MFMA are complete; stages at phase
// distance >=5 are complete (for this wave; cross-wave via barrier observation).
#define WAIT6() do {                                                            \
    asm volatile("s_waitcnt vmcnt(6) lgkmcnt(0)" ::: "memory");                 \
    __builtin_amdgcn_sched_barrier(0);                                          \
  } while (0)

// fence between MFMA and post-reads (keeps read targets' live ranges disjoint)
#define FENCE() __builtin_amdgcn_sched_barrier(0)

// region end: pin everything, workgroup barrier
#define ENDBAR() do {                                                           \
    __builtin_amdgcn_sched_barrier(0);                                          \
    __builtin_amdgcn_s_barrier();                                               \
  } while (0)

  // prologue: 7 half-tiles (tile0 -> buf0; tile1 Ah0,Bh0,Bh1 -> buf1).
  // vmcnt(8) completes s1..s3 (As0.h0, Bs0.h0, Bs0.h1) before the prologue
  // reads and R1's pre-read.
  STG(A, lda, m0, 0, 0, As0);  // s1 buf0.Ah0
  STG(B, ldb, n0, 0, 0, Bs0);  // s2 buf0.Bh0
  STG(B, ldb, n0, 1, 0, Bs0);  // s3 buf0.Bh1
  STG(A, lda, m0, 1, 0, As0);  // s4 buf0.Ah1
  STG(A, lda, m0, 0, 1, As1);  // s5 buf1.Ah0
  STG(B, ldb, n0, 0, 1, Bs1);  // s6 buf1.Bh0
  STG(B, ldb, n0, 1, 1, Bs1);  // s7 buf1.Bh1
  asm volatile("s_waitcnt vmcnt(8)" ::: "memory");
  __builtin_amdgcn_sched_barrier(0);
  __builtin_amdgcn_s_barrier();
  __builtin_amdgcn_sched_barrier(0);

  bf16x8 a_f[2][4], b0[2][2], b1[2][2];
  RD_A(0, 0);        // frags for R1's MFMA
  RD_B(0, 0, b0);

  for (int it = 0; it < NITER; ++it) {
    const int t = it * 2;
    // R1: MFMA(0,0) buf0 | pre-read b1 | stage As1.h1<-t+1
    WAIT6();
    __builtin_amdgcn_s_setprio(1);
    RD_B(0, 1, b1);
    STG(A, lda, m0, 1, t + 1, As1);
    MQ(0, 0, b0);
    __builtin_amdgcn_s_setprio(0);
    ENDBAR();
    // R2: MFMA(0,1) buf0 | stage As0.h0<-t+2 | post-read a_f<-As0.QM1
    WAIT6();
    __builtin_amdgcn_s_setprio(1);
    STG(A, lda, m0, 0, t + 2, As0);
    MQ(0, 1, b1);
    __builtin_amdgcn_s_setprio(0);
    FENCE();
    RD_A(0, 1);
    ENDBAR();
    // R3: MFMA(1,0) buf0 | stage Bs0.h0<-t+2
    WAIT6();
    __builtin_amdgcn_s_setprio(1);
    STG(B, ldb, n0, 0, t + 2, Bs0);
    MQ(1, 0, b0);
    __builtin_amdgcn_s_setprio(0);
    ENDBAR();
    // R4: MFMA(1,1) buf0 | stage Bs0.h1<-t+2 | post-read a_f<-As1.QM0, b0<-Bs1.QN0
    WAIT6();
    __builtin_amdgcn_s_setprio(1);
    STG(B, ldb, n0, 1, t + 2, Bs0);
    MQ(1, 1, b1);
    __builtin_amdgcn_s_setprio(0);
    FENCE();
    RD_A(1, 0);
    RD_B(1, 0, b0);
    ENDBAR();
    // R5: MFMA(0,0) buf1 | pre-read b1<-Bs1.QN1 | stage As0.h1<-t+2
    WAIT6();
    __builtin_amdgcn_s_setprio(1);
    RD_B(1, 1, b1);
    STG(A, lda, m0, 1, t + 2, As0);
    MQ(0, 0, b0);
    __builtin_amdgcn_s_setprio(0);
    ENDBAR();
    // R6: MFMA(0,1) buf1 | stage As1.h0<-t+3 | post-read a_f<-As1.QM1
    WAIT6();
    __builtin_amdgcn_s_setprio(1);
    STG(A, lda, m0, 0, t + 3, As1);
    MQ(0, 1, b1);
    __builtin_amdgcn_s_setprio(0);
    FENCE();
    RD_A(1, 1);
    ENDBAR();
    // R7: MFMA(1,0) buf1 | stage Bs1.h0<-t+3
    WAIT6();
    __builtin_amdgcn_s_setprio(1);
    STG(B, ldb, n0, 0, t + 3, Bs1);
    MQ(1, 0, b0);
    __builtin_amdgcn_s_setprio(0);
    ENDBAR();
    // R8: MFMA(1,1) buf1 | stage Bs1.h1<-t+3 | post-read a_f<-As0.QM0, b0<-Bs0.QN0
    WAIT6();
    __builtin_amdgcn_s_setprio(1);
    STG(B, ldb, n0, 1, t + 3, Bs1);
    MQ(1, 1, b1);
    __builtin_amdgcn_s_setprio(0);
    FENCE();
    RD_A(0, 0);
    RD_B(0, 0, b0);
    ENDBAR();
  }

  // drain pending LDS-DMA and the tail read-ahead
  asm volatile("s_waitcnt vmcnt(0) lgkmcnt(0)" ::: "memory");
  __builtin_amdgcn_sched_barrier(0);

#undef STG
#undef RD_A
#undef RD_B
#undef MQ
#undef WAIT6
#undef FENCE
#undef ENDBAR

  if (MODE == 1) {
    // bf16 store + per-row sum-of-squares accumulation (deferred l2-norm)
    #pragma unroll
    for (int qm = 0; qm < 2; ++qm)
      #pragma unroll
      for (int mi = 0; mi < 4; ++mi) {
        float s2[4] = {0.f, 0.f, 0.f, 0.f};
        #pragma unroll
        for (int qn = 0; qn < 2; ++qn)
          #pragma unroll
          for (int ni = 0; ni < 2; ++ni) {
            const int gc = n0 + qn * 128 + wn * 32 + ni * 16 + fr;
            const float bv = bias[gc];
            #pragma unroll
            for (int r = 0; r < 4; ++r) {
              const int gr = m0 + qm * 128 + wm * 64 + mi * 16 + q * 4 + r;
              float c = acc[qm][qn][mi][ni][r] + bv;
              Cb[(size_t)gr * ldcb + gc] = f2bf(c);
              s2[r] += c * c;
            }
          }
        #pragma unroll
        for (int r = 0; r < 4; ++r) {
          float v = s2[r];
          v += __shfl_xor(v, 1, 64);
          v += __shfl_xor(v, 2, 64);
          v += __shfl_xor(v, 4, 64);
          v += __shfl_xor(v, 8, 64);
          if (fr == 0)
            atomicAdd(Cnorm + (m0 + qm * 128 + wm * 64 + mi * 16 + q * 4 + r), v);
        }
      }
  } else {
    #pragma unroll
    for (int qm = 0; qm < 2; ++qm)
      #pragma unroll
      for (int qn = 0; qn < 2; ++qn)
        #pragma unroll
        for (int ni = 0; ni < 2; ++ni) {
          const int gc = n0 + qn * 128 + wn * 32 + ni * 16 + fr;
          const float bv = bias ? bias[gc] : 0.0f;
          #pragma unroll
          for (int mi = 0; mi < 4; ++mi)
            #pragma unroll
            for (int r = 0; r < 4; ++r) {
              const int gr = m0 + qm * 128 + wm * 64 + mi * 16 + q * 4 + r;
              float c = acc[qm][qn][mi][ni][r] * scale + bv;
              if (MODE == 0) {
                C[(size_t)gr * ldc + gc] = c;
              } else if (MODE == 2) {
                Cb[(size_t)gr * ldcb + gc] = f2bf(c);
              } else {  // MODE 3: fused sigmoid gate
                float g = 1.0f / (1.0f + __expf(-c));
                float x = bf2f(Cb[(size_t)gr * ldcb + gc]);
                float rr = bf2f(Cb[(size_t)gr * ldcb + 1024 + gc]);
                C[(size_t)gr * ldc + gc] = g * x + (1.0f - g) * rr;
              }
            }
        }
  }
}

extern "C" void kernel_launch(void* const* d_in, const int* in_sizes, int n_in,
                              void* d_out, int out_size, void* d_ws, size_t ws_size,
                              hipStream_t stream) {
  const float* X   = (const float*)d_in[0];
  const float* mem = (const float*)d_in[1];
  const float* Wq  = (const float*)d_in[2];
  const float* bq  = (const float*)d_in[3];
  const float* Wk  = (const float*)d_in[4];
  const float* bk  = (const float*)d_in[5];
  const float* Wv  = (const float*)d_in[6];
  const float* bv  = (const float*)d_in[7];
  const float* Wg  = (const float*)d_in[8];
  const float* bg  = (const float*)d_in[9];
  float* out = (float*)d_out;

  const int T = 32768, D = 1024, NS = 512;

  char* p = (char*)d_ws;
  auto alloc = [&](size_t b) { char* r = p; p += (b + 255) & ~(size_t)255; return r; };
  unsigned short* WqT    = (unsigned short*)alloc((size_t)D * D * 2);
  unsigned short* WkvT   = (unsigned short*)alloc((size_t)2 * D * D * 2);
  unsigned short* WgT    = (unsigned short*)alloc((size_t)D * 2 * D * 2);
  unsigned short* memb   = (unsigned short*)alloc((size_t)NS * D * 2);
  float*          bkv    = (float*)alloc((size_t)2 * D * 4);
  float*          KV     = (float*)alloc((size_t)NS * 2 * D * 4);
  unsigned short* Kn     = (unsigned short*)alloc((size_t)NS * D * 2);
  unsigned short* Vt     = (unsigned short*)alloc((size_t)D * NS * 2);
  unsigned short* gatein = (unsigned short*)alloc((size_t)T * 2 * D * 2);  // [T,2048]: X | R
  unsigned short* Qb     = (unsigned short*)alloc((size_t)T * D * 2);      // Q bf16 (unnormalized)
  unsigned short* Wsm    = (unsigned short*)alloc((size_t)T * NS * 2);     // softmax weights bf16
  float*          S      = (float*)alloc((size_t)T * NS * 4);              // scores fp32
  float*          norm2  = (float*)alloc((size_t)T * 4);                   // ||Q_row||^2

  hipMemsetAsync(norm2, 0, (size_t)T * 4, stream);

  // --- prep: weight transposes to [N,K] bf16, converts ---
  k_transpose_bf16<<<dim3(32, 32), dim3(32, 8), 0, stream>>>(Wq, WqT, D, D);
  k_transpose_bf16<<<dim3(32, 32), dim3(32, 8), 0, stream>>>(Wk, WkvT, D, D);
  k_transpose_bf16<<<dim3(32, 32), dim3(32, 8), 0, stream>>>(Wv, WkvT + (size_t)D * D, D, D);
  k_transpose_bf16<<<dim3(32, 64), dim3(32, 8), 0, stream>>>(Wg, WgT, 2 * D, D);
  k_convert_bf16<<<512, 256, 0, stream>>>((const float4*)mem, (ushort4*)memb, NS * D / 4);
  k_concat_bias<<<8, 256, 0, stream>>>(bk, bv, bkv);
  k_stage_x<<<T * D / 4 / 256, 256, 0, stream>>>((const float4*)X, gatein, T * D / 4);

  // --- K,V: [512,2048] = memb @ [Wk|Wv] + [bk|bv] (tiny: old 128^2 kernel) ---
  k_gemm<0><<<dim3(2 * D / 128, NS / 128), 256, 0, stream>>>(
      memb, D, WkvT, D, bkv, 1.0f, KV, 2 * D, nullptr, 0, nullptr, D);
  k_post_kv<<<NS, 256, 0, stream>>>((const float4*)KV, Kn, Vt);

  // --- Q = X @ Wq + bq -> bf16 Qb + row norms (normalization deferred to softmax) ---
  k_gemm256<1><<<dim3(D / 256, T / 256), 512, 0, stream>>>(
      gatein, 2 * D, WqT, D, bq, 1.0f, nullptr, 0, Qb, D, norm2, D);

  // --- scores_raw = Q @ Kn^T (temperature applied in softmax) ---
  k_gemm256<0><<<dim3(NS / 256, T / 256), 512, 0, stream>>>(
      Qb, D, Kn, D, nullptr, 1.0f, S, NS, nullptr, 0, nullptr, D);
  k_softmax<<<T / 4, 256, 0, stream>>>((const float4*)S, norm2, Wsm);

  // --- R = w @ V -> bf16 into gate_in cols 1024.. ---
  k_gemm256<2><<<dim3(D / 256, T / 256), 512, 0, stream>>>(
      Wsm, NS, Vt, NS, nullptr, 1.0f, nullptr, 0, gatein + D, 2 * D, nullptr, NS);

  // --- gate: g = sigmoid([X,R] @ Wg + bg); out = g*x + (1-g)*r ---
  k_gemm256<3><<<dim3(D / 256, T / 256), 512, 0, stream>>>(
      gatein, 2 * D, WgT, 2 * D, bg, 1.0f, out, D, gatein, 2 * D, nullptr, 2 * D);

  (void)in_sizes; (void)n_in; (void)out_size; (void)ws_size;
}